// Round 5
// baseline (564.196 us; speedup 1.0000x reference)
//
#include <hip/hip_runtime.h>

#define EPS 1e-5f

constexpr int NB   = 8;
constexpr int NN   = 2048;
constexpr int DIM  = 128;
constexpr int KNN  = 16;
constexpr int AH   = 512;
constexpr int NPTS = NB * NN;
constexpr float SCALE = 0.08838834764831845f; // 1/sqrt(128)

typedef __attribute__((ext_vector_type(8))) short short8;
typedef __attribute__((ext_vector_type(4))) float floatx4;

__device__ __forceinline__ short f2bf(float f) {
  union { float f; unsigned u; } a; a.f = f;
  unsigned u = a.u;
  unsigned r = (u + 0x7fffu + ((u >> 16) & 1u)) >> 16;  // RNE
  return (short)r;
}
__device__ __forceinline__ float bf2f(short s) {
  union { unsigned u; float f; } a; a.u = ((unsigned)(unsigned short)s) << 16;
  return a.f;
}

// ---------------------------------------------------------------------------
// fp32 tiled GEMM (only Wf = w_in @ w_qkv, tiny). 64x64 tile.
// ---------------------------------------------------------------------------
__global__ __launch_bounds__(256) void gemm_f32(
    const float* __restrict__ A, const float* __restrict__ W,
    float* __restrict__ C, int M, int N, int K)
{
  __shared__ float As[64][33];
  __shared__ float Ws[32][65];
  const int bm = blockIdx.x * 64, bn = blockIdx.y * 64;
  const int tid = threadIdx.x;
  const int tx = tid & 15, ty = tid >> 4;
  float acc[4][4] = {};
  for (int k0 = 0; k0 < K; k0 += 32) {
#pragma unroll
    for (int i = 0; i < 8; ++i) {
      int e = tid + i * 256;
      As[e >> 5][e & 31] = A[(size_t)(bm + (e >> 5)) * K + k0 + (e & 31)];
    }
#pragma unroll
    for (int i = 0; i < 8; ++i) {
      int e = tid + i * 256;
      Ws[e >> 6][e & 63] = W[(size_t)(k0 + (e >> 6)) * N + bn + (e & 63)];
    }
    __syncthreads();
#pragma unroll
    for (int kk = 0; kk < 32; ++kk) {
      float a[4], w[4];
#pragma unroll
      for (int i = 0; i < 4; ++i) a[i] = As[ty * 4 + i][kk];
#pragma unroll
      for (int j = 0; j < 4; ++j) w[j] = Ws[kk][tx * 4 + j];
#pragma unroll
      for (int i = 0; i < 4; ++i)
#pragma unroll
        for (int j = 0; j < 4; ++j)
          acc[i][j] += a[i] * w[j];
    }
    __syncthreads();
  }
#pragma unroll
  for (int i = 0; i < 4; ++i)
#pragma unroll
    for (int j = 0; j < 4; ++j)
      C[(size_t)(bm + ty * 4 + i) * N + bn + tx * 4 + j] = acc[i][j];
}

// ---------------------------------------------------------------------------
// KNN: one wave per point; 32 distances/lane in regs; 16 butterfly-argmin
// rounds; lowest-index tie-break. No LDS/barriers.
// ---------------------------------------------------------------------------
__global__ __launch_bounds__(256) void knn_kernel(
    const float* __restrict__ pos, int* __restrict__ idx_out)
{
  const int tid = threadIdx.x;
  const int lane = tid & 63;
  const int p = blockIdx.x * 4 + (tid >> 6);
  const int b = p >> 11, i = p & (NN - 1);
  const float* pb = pos + (size_t)b * NN * 3;
  const float xi = pb[i * 3], yi = pb[i * 3 + 1], zi = pb[i * 3 + 2];
  const float sqi = xi * xi + yi * yi + zi * zi;
  float v[32];
#pragma unroll
  for (int t = 0; t < 32; ++t) {
    int j = t * 64 + lane;
    float xj = pb[j * 3], yj = pb[j * 3 + 1], zj = pb[j * 3 + 2];
    float sqj = xj * xj + yj * yj + zj * zj;
    float dot = xi * xj + yi * yj + zi * zj;
    v[t] = sqi + sqj - 2.0f * dot;
  }
  for (int s = 0; s < KNN; ++s) {
    float bv = 3.4e38f; int bj = 1 << 30;
#pragma unroll
    for (int t = 0; t < 32; ++t) {
      if (v[t] < bv) { bv = v[t]; bj = t * 64 + lane; }
    }
#pragma unroll
    for (int m = 1; m < 64; m <<= 1) {
      float ov = __shfl_xor(bv, m);
      int   oj = __shfl_xor(bj, m);
      if (ov < bv || (ov == bv && oj < bj)) { bv = ov; bj = oj; }
    }
    if (lane == 0) idx_out[(size_t)p * KNN + s] = bj;
#pragma unroll
    for (int t = 0; t < 32; ++t)
      if (bj == t * 64 + lane) v[t] = 3.4e38f;
  }
}

// ---------------------------------------------------------------------------
// Pack weights into bf16 B-fragment layouts (frag f at [f*512 + lane*8 + j],
// value = W[k = ks*32 + q*8 + j][n]) + folded BN + biases.
// ---------------------------------------------------------------------------
__global__ __launch_bounds__(256) void pack_weights(
    const float* __restrict__ attn_w1, const float* __restrict__ attn_w2,
    const float* __restrict__ pos_w2, const float* __restrict__ Wf,
    const float* __restrict__ w_out,
    const float* __restrict__ attn_b1, const float* __restrict__ abn_g,
    const float* __restrict__ abn_b, const float* __restrict__ abn_m,
    const float* __restrict__ abn_v,
    const float* __restrict__ pos_b1, const float* __restrict__ pbn_g,
    const float* __restrict__ pbn_b, const float* __restrict__ pbn_m,
    const float* __restrict__ pbn_v, const float* __restrict__ pos_b2,
    short* __restrict__ w1p, short* __restrict__ w2p, short* __restrict__ pw2p,
    short* __restrict__ wfp, short* __restrict__ wop,
    float* __restrict__ biasq,
    float* __restrict__ t1sc, float* __restrict__ t1bi,
    float* __restrict__ phsc, float* __restrict__ phbi)
{
  int t = blockIdx.x * 256 + threadIdx.x;
  if (t < 65536) {                       // w1p: [128x512], 8 chunks of 64 cols
    int j = t & 7, lane = (t >> 3) & 63, ks = (t >> 9) & 3, nt = (t >> 11) & 3, ch = t >> 13;
    int q = lane >> 4, cc = lane & 15;
    int k = ks * 32 + q * 8 + j, n = ch * 64 + nt * 16 + cc;
    w1p[t] = f2bf(attn_w1[(size_t)k * AH + n]);
  } else if (t < 131072) {               // w2p: [512x128], 8 chunks of 64 rows
    int e = t - 65536;
    int j = e & 7, lane = (e >> 3) & 63, ks = (e >> 9) & 1, nt = (e >> 10) & 7, ch = e >> 13;
    int q = lane >> 4, cc = lane & 15;
    int k = ch * 64 + ks * 32 + q * 8 + j, n = nt * 16 + cc;
    w2p[e] = f2bf(attn_w2[(size_t)k * DIM + n]);
  } else if (t < 139264) {               // pw2p: pos_w2 [64x128]
    int e = t - 131072;
    int j = e & 7, lane = (e >> 3) & 63, ks = (e >> 9) & 1, nt = e >> 10;
    int q = lane >> 4, cc = lane & 15;
    int k = ks * 32 + q * 8 + j, n = nt * 16 + cc;
    pw2p[e] = f2bf(pos_w2[(size_t)k * DIM + n]);
  } else if (t < 188416) {               // wfp: Wf [128x384], 3 col-chunks
    int e = t - 139264;
    int j = e & 7, lane = (e >> 3) & 63, ks = (e >> 9) & 3, nt = (e >> 11) & 7, nc = e >> 14;
    int q = lane >> 4, cc = lane & 15;
    int k = ks * 32 + q * 8 + j, n = nc * 128 + nt * 16 + cc;
    wfp[e] = f2bf(Wf[(size_t)k * 384 + n]);
  } else if (t < 204800) {               // wop: w_out [128x128]
    int e = t - 188416;
    int j = e & 7, lane = (e >> 3) & 63, ks = (e >> 9) & 3, nt = (e >> 11) & 7;
    int q = lane >> 4, cc = lane & 15;
    int k = ks * 32 + q * 8 + j, n = nt * 16 + cc;
    wop[e] = f2bf(w_out[(size_t)k * DIM + n]);
  } else if (t < 205184) {               // biasq[384]: pos_b2 into q,v cols
    int c = t - 204800;
    biasq[c] = (c < 128) ? pos_b2[c] : ((c < 256) ? 0.0f : pos_b2[c - 256]);
  } else if (t < 205696) {
    int c = t - 205184;
    t1sc[c] = abn_g[c] * rsqrtf(abn_v[c] + EPS);
  } else if (t < 206208) {
    int c = t - 205696;
    float sc = abn_g[c] * rsqrtf(abn_v[c] + EPS);
    t1bi[c] = (attn_b1[c] - abn_m[c]) * sc + abn_b[c];
  } else if (t < 206272) {
    int c = t - 206208;
    phsc[c] = pbn_g[c] * rsqrtf(pbn_v[c] + EPS);
  } else if (t < 206336) {
    int c = t - 206272;
    float sc = pbn_g[c] * rsqrtf(pbn_v[c] + EPS);
    phbi[c] = (pos_b1[c] - pbn_m[c]) * sc + pbn_b[c];
  }
}

// ---------------------------------------------------------------------------
// MFMA GEMM: qkv[16384x384] (bf16 out) = bf16(ori_x) @ wfp + biasq.
// ---------------------------------------------------------------------------
__global__ __launch_bounds__(256, 2) void gemm_in(
    const float* __restrict__ A, const short* __restrict__ wfp,
    const float* __restrict__ biasq, short* __restrict__ C)
{
  __shared__ short As[128 * 128];
  const int tid = threadIdx.x;
  const int lane = tid & 63, w = tid >> 6;
  const int wr = w >> 1, wc = w & 1;
  const int q = lane >> 4, cc = lane & 15;
  const int row0 = blockIdx.x * 128;
  const int nc = blockIdx.y;
#pragma unroll
  for (int it = 0; it < 8; ++it) {
    int row = (tid >> 4) + it * 16, cg = tid & 15;
    const float* src = A + (size_t)(row0 + row) * 128 + cg * 8;
    float4 f0 = *(const float4*)src, f1 = *(const float4*)(src + 4);
    short8 v;
    v[0] = f2bf(f0.x); v[1] = f2bf(f0.y); v[2] = f2bf(f0.z); v[3] = f2bf(f0.w);
    v[4] = f2bf(f1.x); v[5] = f2bf(f1.y); v[6] = f2bf(f1.z); v[7] = f2bf(f1.w);
    *(short8*)(As + row * 128 + ((cg ^ (row & 15)) << 3)) = v;
  }
  __syncthreads();
  floatx4 acc[4][4];
#pragma unroll
  for (int i = 0; i < 4; ++i)
#pragma unroll
    for (int jt = 0; jt < 4; ++jt) acc[i][jt] = (floatx4){0.f, 0.f, 0.f, 0.f};
#pragma unroll
  for (int ks = 0; ks < 4; ++ks) {
    short8 a8[4], b8[4];
#pragma unroll
    for (int i = 0; i < 4; ++i) {
      int row = (wr * 4 + i) * 16 + cc;
      a8[i] = *(const short8*)(As + row * 128 + (((ks * 4 + q) ^ cc) << 3));
    }
#pragma unroll
    for (int jt = 0; jt < 4; ++jt)
      b8[jt] = *(const short8*)(wfp + ((((nc * 8 + wc * 4 + jt) * 4 + ks) * 64 + lane) << 3));
#pragma unroll
    for (int i = 0; i < 4; ++i)
#pragma unroll
      for (int jt = 0; jt < 4; ++jt)
        acc[i][jt] = __builtin_amdgcn_mfma_f32_16x16x32_bf16(a8[i], b8[jt], acc[i][jt], 0, 0, 0);
  }
#pragma unroll
  for (int jt = 0; jt < 4; ++jt) {
    int colG = nc * 128 + (wc * 4 + jt) * 16 + cc;
    float bv = biasq[colG];
#pragma unroll
    for (int i = 0; i < 4; ++i)
#pragma unroll
      for (int r = 0; r < 4; ++r) {
        int row = (wr * 4 + i) * 16 + q * 4 + r;
        C[(size_t)(row0 + row) * 384 + colG] = f2bf(acc[i][jt][r] + bv);
      }
  }
}

// ---------------------------------------------------------------------------
// MFMA GEMM: out[16384x128] = bf16(agg) @ wop + ori_x (fp32 residual).
// ---------------------------------------------------------------------------
__global__ __launch_bounds__(256, 2) void gemm_out(
    const float* __restrict__ A, const short* __restrict__ wop,
    const float* __restrict__ R, float* __restrict__ C)
{
  __shared__ short As[128 * 128];
  const int tid = threadIdx.x;
  const int lane = tid & 63, w = tid >> 6;
  const int wr = w >> 1, wc = w & 1;
  const int q = lane >> 4, cc = lane & 15;
  const int row0 = blockIdx.x * 128;
#pragma unroll
  for (int it = 0; it < 8; ++it) {
    int row = (tid >> 4) + it * 16, cg = tid & 15;
    const float* src = A + (size_t)(row0 + row) * 128 + cg * 8;
    float4 f0 = *(const float4*)src, f1 = *(const float4*)(src + 4);
    short8 v;
    v[0] = f2bf(f0.x); v[1] = f2bf(f0.y); v[2] = f2bf(f0.z); v[3] = f2bf(f0.w);
    v[4] = f2bf(f1.x); v[5] = f2bf(f1.y); v[6] = f2bf(f1.z); v[7] = f2bf(f1.w);
    *(short8*)(As + row * 128 + ((cg ^ (row & 15)) << 3)) = v;
  }
  __syncthreads();
  floatx4 acc[4][4];
#pragma unroll
  for (int i = 0; i < 4; ++i)
#pragma unroll
    for (int jt = 0; jt < 4; ++jt) acc[i][jt] = (floatx4){0.f, 0.f, 0.f, 0.f};
#pragma unroll
  for (int ks = 0; ks < 4; ++ks) {
    short8 a8[4], b8[4];
#pragma unroll
    for (int i = 0; i < 4; ++i) {
      int row = (wr * 4 + i) * 16 + cc;
      a8[i] = *(const short8*)(As + row * 128 + (((ks * 4 + q) ^ cc) << 3));
    }
#pragma unroll
    for (int jt = 0; jt < 4; ++jt)
      b8[jt] = *(const short8*)(wop + ((((wc * 4 + jt) * 4 + ks) * 64 + lane) << 3));
#pragma unroll
    for (int i = 0; i < 4; ++i)
#pragma unroll
      for (int jt = 0; jt < 4; ++jt)
        acc[i][jt] = __builtin_amdgcn_mfma_f32_16x16x32_bf16(a8[i], b8[jt], acc[i][jt], 0, 0, 0);
  }
#pragma unroll
  for (int jt = 0; jt < 4; ++jt) {
    int col = (wc * 4 + jt) * 16 + cc;
#pragma unroll
    for (int i = 0; i < 4; ++i)
#pragma unroll
      for (int r = 0; r < 4; ++r) {
        int row = (wr * 4 + i) * 16 + q * 4 + r;
        size_t o = (size_t)(row0 + row) * 128 + col;
        C[o] = acc[i][jt][r] + R[o];
      }
  }
}

// ---------------------------------------------------------------------------
// Fused MFMA attention: 8 points/block (M=128), 4 waves, 64-col AH chunks,
// double-buffered t1. Two-pass prologue: pe staged through a_s (LDS) so the
// 64 pe registers never overlap the gather/pack phase (anti-spill).
// LDS 68.5 KB -> 2 blocks/CU.
// ---------------------------------------------------------------------------
__global__ __launch_bounds__(256, 2) void fused_attn(
    const float* __restrict__ pos, const short* __restrict__ qkv,
    const int* __restrict__ knn_idx,
    const float* __restrict__ pos_w1,
    const short* __restrict__ w1p, const short* __restrict__ w2p,
    const short* __restrict__ pw2p,
    const float* __restrict__ t1sc, const float* __restrict__ t1bi,
    const float* __restrict__ phsc, const float* __restrict__ phbi,
    const float* __restrict__ attn_b2,
    float* __restrict__ agg)
{
  __shared__ short a_s[128 * 128];      // 32 KB, XOR swizzle on row&15
  __shared__ short t1_s[2][128 * 64];   // 32 KB, XOR swizzle on row&7
  __shared__ short q_ss[8 * 128];       // 2 KB bf16 q rows
  __shared__ float relp_s[128 * 4];
  __shared__ int   nbr_s[128];

  const int tid = threadIdx.x;
  const int lane = tid & 63, w = tid >> 6;
  const int wr = w >> 1, wc = w & 1;
  const int q = lane >> 4, cc = lane & 15;
  const int gp0 = blockIdx.x * 8;
  const int bb = gp0 >> 11;
  const int n0 = gp0 & (NN - 1);

  if (tid < 128) nbr_s[tid] = knn_idx[(size_t)gp0 * KNN + tid];
  if (tid >= 128) {  // stage q rows (bf16): 128 short8 chunks
    int e = tid - 128;
    int p = e >> 4, seg = e & 15;
    *(short8*)(q_ss + p * 128 + seg * 8) =
        *(const short8*)(qkv + (size_t)(gp0 + p) * 384 + seg * 8);
  }
  __syncthreads();
  if (tid < 128) {
    int p = tid >> 4;
    int j = nbr_s[tid];
    const float* pa = pos + ((size_t)bb * NN + n0 + p) * 3;
    const float* pj = pos + ((size_t)bb * NN + j) * 3;
    relp_s[tid * 4 + 0] = pa[0] - pj[0];
    relp_s[tid * 4 + 1] = pa[1] - pj[1];
    relp_s[tid * 4 + 2] = pa[2] - pj[2];
  }
  __syncthreads();

  // ph = relu(bn(relp @ pos_w1 + b1)) -> t1_s[0]
#pragma unroll
  for (int r2 = 0; r2 < 32; ++r2) {
    int e = tid + r2 * 256;
    int row = e >> 6, c = e & 63;
    float lin = relp_s[row * 4] * pos_w1[c] + relp_s[row * 4 + 1] * pos_w1[64 + c]
              + relp_s[row * 4 + 2] * pos_w1[128 + c];
    t1_s[0][row * 64 + (((c >> 3) ^ (row & 7)) << 3) + (c & 7)] =
        f2bf(fmaxf(lin * phsc[c] + phbi[c], 0.0f));
  }
  __syncthreads();

  // --- Pass A: pe = ph @ pos_w2 -> bf16 into a_s (pe regs die here) ---
  {
    floatx4 pe[4][4];
#pragma unroll
    for (int i = 0; i < 4; ++i)
#pragma unroll
      for (int jt = 0; jt < 4; ++jt) pe[i][jt] = (floatx4){0.f, 0.f, 0.f, 0.f};
#pragma unroll
    for (int ks = 0; ks < 2; ++ks) {
      short8 a8[4];
#pragma unroll
      for (int i = 0; i < 4; ++i) {
        int row = (wr * 4 + i) * 16 + cc;
        a8[i] = *(const short8*)(t1_s[0] + row * 64 + (((ks * 4 + q) ^ (row & 7)) << 3));
      }
#pragma unroll
      for (int jt = 0; jt < 4; ++jt) {
        short8 b8 = *(const short8*)(pw2p + ((((wc * 4 + jt) * 2 + ks) * 64 + lane) << 3));
#pragma unroll
        for (int i = 0; i < 4; ++i)
          pe[i][jt] = __builtin_amdgcn_mfma_f32_16x16x32_bf16(a8[i], b8, pe[i][jt], 0, 0, 0);
      }
    }
#pragma unroll
    for (int i = 0; i < 4; ++i) {
      int p = wr * 4 + i;
#pragma unroll
      for (int jt = 0; jt < 4; ++jt) {
        int col = (wc * 4 + jt) * 16 + cc;
#pragma unroll
        for (int r = 0; r < 4; ++r) {
          int row = p * 16 + q * 4 + r;
          a_s[row * 128 + (((col >> 3) ^ (row & 15)) << 3) + (col & 7)] =
              f2bf(pe[i][jt][r]);
        }
      }
    }
  }
  // No barrier: pass B touches exactly the slots this thread wrote.

  // --- Pass B: gather k/v; a = q - k + pe (in place); vpe -> packed regs ---
  unsigned vpe_pk[4][4][2];
#pragma unroll
  for (int i = 0; i < 4; ++i) {
    int p = wr * 4 + i;
#pragma unroll
    for (int jt = 0; jt < 4; ++jt) {
      int col = (wc * 4 + jt) * 16 + cc;
      float qv = bf2f(q_ss[p * 128 + col]);
      short vb[4];
#pragma unroll
      for (int r = 0; r < 4; ++r) {
        int row = p * 16 + q * 4 + r;
        const short* kv = qkv + ((size_t)bb * NN + nbr_s[row]) * 384;
        int slot = row * 128 + (((col >> 3) ^ (row & 15)) << 3) + (col & 7);
        float pev = bf2f(a_s[slot]);
        a_s[slot] = f2bf(qv - bf2f(kv[128 + col]) + pev);
        vb[r] = f2bf(bf2f(kv[256 + col]) + pev);
      }
      vpe_pk[i][jt][0] = ((unsigned)(unsigned short)vb[1] << 16) | (unsigned short)vb[0];
      vpe_pk[i][jt][1] = ((unsigned)(unsigned short)vb[3] << 16) | (unsigned short)vb[2];
    }
  }
  __syncthreads();   // a_s fully built

  floatx4 hacc[4][4];
#pragma unroll
  for (int i = 0; i < 4; ++i)
#pragma unroll
    for (int jt = 0; jt < 4; ++jt) hacc[i][jt] = (floatx4){0.f, 0.f, 0.f, 0.f};

  for (int ch = 0; ch < 8; ++ch) {
    short* t1b = t1_s[ch & 1];
    // GEMM1: tacc = a @ w1[:, ch*64 : +64]  (wave covers 32 cols)
    floatx4 tacc[4][2];
#pragma unroll
    for (int i = 0; i < 4; ++i)
#pragma unroll
      for (int jt = 0; jt < 2; ++jt) tacc[i][jt] = (floatx4){0.f, 0.f, 0.f, 0.f};
#pragma unroll
    for (int ks = 0; ks < 4; ++ks) {
      short8 a8[4], b8[2];
#pragma unroll
      for (int i = 0; i < 4; ++i) {
        int row = (wr * 4 + i) * 16 + cc;
        a8[i] = *(const short8*)(a_s + row * 128 + (((ks * 4 + q) ^ cc) << 3));
      }
#pragma unroll
      for (int jt = 0; jt < 2; ++jt)
        b8[jt] = *(const short8*)(w1p + ((((ch * 4 + wc * 2 + jt) * 4 + ks) * 64 + lane) << 3));
#pragma unroll
      for (int i = 0; i < 4; ++i)
#pragma unroll
        for (int jt = 0; jt < 2; ++jt)
          tacc[i][jt] = __builtin_amdgcn_mfma_f32_16x16x32_bf16(a8[i], b8[jt], tacc[i][jt], 0, 0, 0);
    }
    // bn/relu -> t1b (64-col, swizzled)
#pragma unroll
    for (int jt = 0; jt < 2; ++jt) {
      int colL = (wc * 2 + jt) * 16 + cc;
      int colG = ch * 64 + colL;
      float sc = t1sc[colG], bi = t1bi[colG];
#pragma unroll
      for (int i = 0; i < 4; ++i)
#pragma unroll
        for (int r = 0; r < 4; ++r) {
          int row = (wr * 4 + i) * 16 + q * 4 + r;
          t1b[row * 64 + (((colL >> 3) ^ (row & 7)) << 3) + (colL & 7)] =
              f2bf(fmaxf(tacc[i][jt][r] * sc + bi, 0.0f));
        }
    }
    __syncthreads();   // t1b visible; ping-pong keeps chunk ch-1 reads safe
    // GEMM2: hacc += t1 @ w2[ch*64 : +64, :]
#pragma unroll
    for (int ks = 0; ks < 2; ++ks) {
      short8 a8[4], b8[4];
#pragma unroll
      for (int i = 0; i < 4; ++i) {
        int row = (wr * 4 + i) * 16 + cc;
        a8[i] = *(const short8*)(t1b + row * 64 + (((ks * 4 + q) ^ (row & 7)) << 3));
      }
#pragma unroll
      for (int jt = 0; jt < 4; ++jt)
        b8[jt] = *(const short8*)(w2p + ((((ch * 8 + wc * 4 + jt) * 2 + ks) * 64 + lane) << 3));
#pragma unroll
      for (int i = 0; i < 4; ++i)
#pragma unroll
        for (int jt = 0; jt < 4; ++jt)
          hacc[i][jt] = __builtin_amdgcn_mfma_f32_16x16x32_bf16(a8[i], b8[jt], hacc[i][jt], 0, 0, 0);
    }
  }

  // softmax over the 16 neighbors per (point, channel) + aggregate
#pragma unroll
  for (int i = 0; i < 4; ++i) {
    int p = wr * 4 + i;
#pragma unroll
    for (int jt = 0; jt < 4; ++jt) {
      int col = (wc * 4 + jt) * 16 + cc;
      float b2v = attn_b2[col];
      float v0[4], mx = -3.4e38f;
#pragma unroll
      for (int r = 0; r < 4; ++r) {
        v0[r] = (hacc[i][jt][r] + b2v) * SCALE;
        mx = fmaxf(mx, v0[r]);
      }
      mx = fmaxf(mx, __shfl_xor(mx, 16));
      mx = fmaxf(mx, __shfl_xor(mx, 32));
      float ex[4], sum = 0.f;
#pragma unroll
      for (int r = 0; r < 4; ++r) { ex[r] = __expf(v0[r] - mx); sum += ex[r]; }
      sum += __shfl_xor(sum, 16);
      sum += __shfl_xor(sum, 32);
      float inv = 1.0f / sum;
      float vv[4];
      vv[0] = bf2f((short)(vpe_pk[i][jt][0] & 0xffff));
      vv[1] = bf2f((short)(vpe_pk[i][jt][0] >> 16));
      vv[2] = bf2f((short)(vpe_pk[i][jt][1] & 0xffff));
      vv[3] = bf2f((short)(vpe_pk[i][jt][1] >> 16));
      float part = 0.f;
#pragma unroll
      for (int r = 0; r < 4; ++r) part += ex[r] * vv[r];
      part += __shfl_xor(part, 16);
      part += __shfl_xor(part, 32);
      if (q == 0) agg[(size_t)(gp0 + p) * DIM + col] = part * inv;
    }
  }
}

extern "C" void kernel_launch(void* const* d_in, const int* in_sizes, int n_in,
                              void* d_out, int out_size, void* d_ws, size_t ws_size,
                              hipStream_t stream)
{
  const float* ori_x    = (const float*)d_in[0];
  const float* pos      = (const float*)d_in[1];
  const float* w_in     = (const float*)d_in[2];
  const float* w_qkv    = (const float*)d_in[3];
  const float* w_out    = (const float*)d_in[4];
  const float* pos_w1   = (const float*)d_in[5];
  const float* pos_b1   = (const float*)d_in[6];
  const float* pos_bn_g = (const float*)d_in[7];
  const float* pos_bn_b = (const float*)d_in[8];
  const float* pos_bn_m = (const float*)d_in[9];
  const float* pos_bn_v = (const float*)d_in[10];
  const float* pos_w2   = (const float*)d_in[11];
  const float* pos_b2   = (const float*)d_in[12];
  const float* attn_w1  = (const float*)d_in[13];
  const float* attn_b1  = (const float*)d_in[14];
  const float* attn_bn_g = (const float*)d_in[15];
  const float* attn_bn_b = (const float*)d_in[16];
  const float* attn_bn_m = (const float*)d_in[17];
  const float* attn_bn_v = (const float*)d_in[18];
  const float* attn_w2  = (const float*)d_in[19];
  const float* attn_b2  = (const float*)d_in[20];
  float* out = (float*)d_out;

  float* agg  = (float*)d_ws;                          // [NPTS*128] f32; Wf aliases head
  float* Wf   = agg;                                   // [128*384] (consumed by pack)
  short* qkvb = (short*)(agg + (size_t)NPTS * DIM);    // [NPTS*384] bf16
  int*   idx  = (int*)(qkvb + (size_t)NPTS * 3 * DIM); // [NPTS*16]
  short* w1p  = (short*)(idx + (size_t)NPTS * KNN);
  short* w2p  = w1p + 65536;
  short* pw2p = w2p + 65536;
  short* wfp  = pw2p + 8192;
  short* wop  = wfp + 49152;
  float* biasq = (float*)(wop + 16384);
  float* t1sc = biasq + 384;
  float* t1bi = t1sc + 512;
  float* phsc = t1bi + 512;
  float* phbi = phsc + 64;

  gemm_f32<<<dim3(2, 6), 256, 0, stream>>>(w_in, w_qkv, Wf, 128, 384, 128);
  pack_weights<<<807, 256, 0, stream>>>(attn_w1, attn_w2, pos_w2, Wf, w_out,
      attn_b1, attn_bn_g, attn_bn_b, attn_bn_m, attn_bn_v,
      pos_b1, pos_bn_g, pos_bn_b, pos_bn_m, pos_bn_v, pos_b2,
      w1p, w2p, pw2p, wfp, wop, biasq, t1sc, t1bi, phsc, phbi);
  gemm_in<<<dim3(NPTS / 128, 3), 256, 0, stream>>>(ori_x, wfp, biasq, qkvb);
  knn_kernel<<<NPTS / 4, 256, 0, stream>>>(pos, idx);
  fused_attn<<<NPTS / 8, 256, 0, stream>>>(pos, qkvb, idx, pos_w1,
      w1p, w2p, pw2p, t1sc, t1bi, phsc, phbi, attn_b2, agg);
  gemm_out<<<NPTS / 128, 256, 0, stream>>>(agg, wop, ori_x, out);
}

// Round 6
// 451.078 us; speedup vs baseline: 1.2508x; 1.2508x over previous
//
#include <hip/hip_runtime.h>

#define EPS 1e-5f

constexpr int NB   = 8;
constexpr int NN   = 2048;
constexpr int DIM  = 128;
constexpr int KNN  = 16;
constexpr int AH   = 512;
constexpr int NPTS = NB * NN;
constexpr float SCALE = 0.08838834764831845f; // 1/sqrt(128)

typedef __attribute__((ext_vector_type(8))) short short8;
typedef __attribute__((ext_vector_type(4))) float floatx4;

__device__ __forceinline__ short f2bf(float f) {
  union { float f; unsigned u; } a; a.f = f;
  unsigned u = a.u;
  unsigned r = (u + 0x7fffu + ((u >> 16) & 1u)) >> 16;  // RNE
  return (short)r;
}
__device__ __forceinline__ float bf2f(short s) {
  union { unsigned u; float f; } a; a.u = ((unsigned)(unsigned short)s) << 16;
  return a.f;
}

// ---------------------------------------------------------------------------
// fp32 tiled GEMM (only Wf = w_in @ w_qkv, tiny). 64x64 tile.
// ---------------------------------------------------------------------------
__global__ __launch_bounds__(256) void gemm_f32(
    const float* __restrict__ A, const float* __restrict__ W,
    float* __restrict__ C, int M, int N, int K)
{
  __shared__ float As[64][33];
  __shared__ float Ws[32][65];
  const int bm = blockIdx.x * 64, bn = blockIdx.y * 64;
  const int tid = threadIdx.x;
  const int tx = tid & 15, ty = tid >> 4;
  float acc[4][4] = {};
  for (int k0 = 0; k0 < K; k0 += 32) {
#pragma unroll
    for (int i = 0; i < 8; ++i) {
      int e = tid + i * 256;
      As[e >> 5][e & 31] = A[(size_t)(bm + (e >> 5)) * K + k0 + (e & 31)];
    }
#pragma unroll
    for (int i = 0; i < 8; ++i) {
      int e = tid + i * 256;
      Ws[e >> 6][e & 63] = W[(size_t)(k0 + (e >> 6)) * N + bn + (e & 63)];
    }
    __syncthreads();
#pragma unroll
    for (int kk = 0; kk < 32; ++kk) {
      float a[4], w[4];
#pragma unroll
      for (int i = 0; i < 4; ++i) a[i] = As[ty * 4 + i][kk];
#pragma unroll
      for (int j = 0; j < 4; ++j) w[j] = Ws[kk][tx * 4 + j];
#pragma unroll
      for (int i = 0; i < 4; ++i)
#pragma unroll
        for (int j = 0; j < 4; ++j)
          acc[i][j] += a[i] * w[j];
    }
    __syncthreads();
  }
#pragma unroll
  for (int i = 0; i < 4; ++i)
#pragma unroll
    for (int j = 0; j < 4; ++j)
      C[(size_t)(bm + ty * 4 + i) * N + bn + tx * 4 + j] = acc[i][j];
}

// ---------------------------------------------------------------------------
// KNN: one wave per point; 32 distances/lane in regs; 16 butterfly-argmin
// rounds; lowest-index tie-break. No LDS/barriers.
// ---------------------------------------------------------------------------
__global__ __launch_bounds__(256) void knn_kernel(
    const float* __restrict__ pos, int* __restrict__ idx_out)
{
  const int tid = threadIdx.x;
  const int lane = tid & 63;
  const int p = blockIdx.x * 4 + (tid >> 6);
  const int b = p >> 11, i = p & (NN - 1);
  const float* pb = pos + (size_t)b * NN * 3;
  const float xi = pb[i * 3], yi = pb[i * 3 + 1], zi = pb[i * 3 + 2];
  const float sqi = xi * xi + yi * yi + zi * zi;
  float v[32];
#pragma unroll
  for (int t = 0; t < 32; ++t) {
    int j = t * 64 + lane;
    float xj = pb[j * 3], yj = pb[j * 3 + 1], zj = pb[j * 3 + 2];
    float sqj = xj * xj + yj * yj + zj * zj;
    float dot = xi * xj + yi * yj + zi * zj;
    v[t] = sqi + sqj - 2.0f * dot;
  }
  for (int s = 0; s < KNN; ++s) {
    float bv = 3.4e38f; int bj = 1 << 30;
#pragma unroll
    for (int t = 0; t < 32; ++t) {
      if (v[t] < bv) { bv = v[t]; bj = t * 64 + lane; }
    }
#pragma unroll
    for (int m = 1; m < 64; m <<= 1) {
      float ov = __shfl_xor(bv, m);
      int   oj = __shfl_xor(bj, m);
      if (ov < bv || (ov == bv && oj < bj)) { bv = ov; bj = oj; }
    }
    if (lane == 0) idx_out[(size_t)p * KNN + s] = bj;
#pragma unroll
    for (int t = 0; t < 32; ++t)
      if (bj == t * 64 + lane) v[t] = 3.4e38f;
  }
}

// ---------------------------------------------------------------------------
// Pack weights into bf16 B-fragment layouts (frag f at [f*512 + lane*8 + j],
// value = W[k = ks*32 + q*8 + j][n]) + folded BN + biases.
// ---------------------------------------------------------------------------
__global__ __launch_bounds__(256) void pack_weights(
    const float* __restrict__ attn_w1, const float* __restrict__ attn_w2,
    const float* __restrict__ pos_w2, const float* __restrict__ Wf,
    const float* __restrict__ w_out,
    const float* __restrict__ attn_b1, const float* __restrict__ abn_g,
    const float* __restrict__ abn_b, const float* __restrict__ abn_m,
    const float* __restrict__ abn_v,
    const float* __restrict__ pos_b1, const float* __restrict__ pbn_g,
    const float* __restrict__ pbn_b, const float* __restrict__ pbn_m,
    const float* __restrict__ pbn_v, const float* __restrict__ pos_b2,
    short* __restrict__ w1p, short* __restrict__ w2p, short* __restrict__ pw2p,
    short* __restrict__ wfp, short* __restrict__ wop,
    float* __restrict__ biasq,
    float* __restrict__ t1sc, float* __restrict__ t1bi,
    float* __restrict__ phsc, float* __restrict__ phbi)
{
  int t = blockIdx.x * 256 + threadIdx.x;
  if (t < 65536) {                       // w1p: [128x512], 8 chunks of 64 cols
    int j = t & 7, lane = (t >> 3) & 63, ks = (t >> 9) & 3, nt = (t >> 11) & 3, ch = t >> 13;
    int q = lane >> 4, cc = lane & 15;
    int k = ks * 32 + q * 8 + j, n = ch * 64 + nt * 16 + cc;
    w1p[t] = f2bf(attn_w1[(size_t)k * AH + n]);
  } else if (t < 131072) {               // w2p: [512x128], 8 chunks of 64 rows
    int e = t - 65536;
    int j = e & 7, lane = (e >> 3) & 63, ks = (e >> 9) & 1, nt = (e >> 10) & 7, ch = e >> 13;
    int q = lane >> 4, cc = lane & 15;
    int k = ch * 64 + ks * 32 + q * 8 + j, n = nt * 16 + cc;
    w2p[e] = f2bf(attn_w2[(size_t)k * DIM + n]);
  } else if (t < 139264) {               // pw2p: pos_w2 [64x128]
    int e = t - 131072;
    int j = e & 7, lane = (e >> 3) & 63, ks = (e >> 9) & 1, nt = e >> 10;
    int q = lane >> 4, cc = lane & 15;
    int k = ks * 32 + q * 8 + j, n = nt * 16 + cc;
    pw2p[e] = f2bf(pos_w2[(size_t)k * DIM + n]);
  } else if (t < 188416) {               // wfp: Wf [128x384], 3 col-chunks
    int e = t - 139264;
    int j = e & 7, lane = (e >> 3) & 63, ks = (e >> 9) & 3, nt = (e >> 11) & 7, nc = e >> 14;
    int q = lane >> 4, cc = lane & 15;
    int k = ks * 32 + q * 8 + j, n = nc * 128 + nt * 16 + cc;
    wfp[e] = f2bf(Wf[(size_t)k * 384 + n]);
  } else if (t < 204800) {               // wop: w_out [128x128]
    int e = t - 188416;
    int j = e & 7, lane = (e >> 3) & 63, ks = (e >> 9) & 3, nt = (e >> 11) & 7;
    int q = lane >> 4, cc = lane & 15;
    int k = ks * 32 + q * 8 + j, n = nt * 16 + cc;
    wop[e] = f2bf(w_out[(size_t)k * DIM + n]);
  } else if (t < 205184) {               // biasq[384]: pos_b2 into q,v cols
    int c = t - 204800;
    biasq[c] = (c < 128) ? pos_b2[c] : ((c < 256) ? 0.0f : pos_b2[c - 256]);
  } else if (t < 205696) {
    int c = t - 205184;
    t1sc[c] = abn_g[c] * rsqrtf(abn_v[c] + EPS);
  } else if (t < 206208) {
    int c = t - 205696;
    float sc = abn_g[c] * rsqrtf(abn_v[c] + EPS);
    t1bi[c] = (attn_b1[c] - abn_m[c]) * sc + abn_b[c];
  } else if (t < 206272) {
    int c = t - 206208;
    phsc[c] = pbn_g[c] * rsqrtf(pbn_v[c] + EPS);
  } else if (t < 206336) {
    int c = t - 206272;
    float sc = pbn_g[c] * rsqrtf(pbn_v[c] + EPS);
    phbi[c] = (pos_b1[c] - pbn_m[c]) * sc + pbn_b[c];
  }
}

// ---------------------------------------------------------------------------
// MFMA GEMM: qkv[16384x384] (bf16 out) = bf16(ori_x) @ wfp + biasq.
// M=64 blocks, 4 waves each 32x64 of the 64x128 col-chunk. No spill.
// ---------------------------------------------------------------------------
__global__ __launch_bounds__(256, 4) void gemm_in(
    const float* __restrict__ A, const short* __restrict__ wfp,
    const float* __restrict__ biasq, short* __restrict__ C)
{
  __shared__ short As[64 * 128];
  const int tid = threadIdx.x;
  const int lane = tid & 63, w = tid >> 6;
  const int wr = w >> 1, wc = w & 1;
  const int q = lane >> 4, cc = lane & 15;
  const int row0 = blockIdx.x * 64;
  const int nc = blockIdx.y;
#pragma unroll
  for (int it = 0; it < 4; ++it) {
    int e = tid + it * 256;
    int row = e >> 4, cg = e & 15;
    const float* src = A + (size_t)(row0 + row) * 128 + cg * 8;
    float4 f0 = *(const float4*)src, f1 = *(const float4*)(src + 4);
    short8 v;
    v[0] = f2bf(f0.x); v[1] = f2bf(f0.y); v[2] = f2bf(f0.z); v[3] = f2bf(f0.w);
    v[4] = f2bf(f1.x); v[5] = f2bf(f1.y); v[6] = f2bf(f1.z); v[7] = f2bf(f1.w);
    *(short8*)(As + row * 128 + ((cg ^ (row & 15)) << 3)) = v;
  }
  __syncthreads();
  floatx4 acc[2][4];
#pragma unroll
  for (int i = 0; i < 2; ++i)
#pragma unroll
    for (int jt = 0; jt < 4; ++jt) acc[i][jt] = (floatx4){0.f, 0.f, 0.f, 0.f};
#pragma unroll
  for (int ks = 0; ks < 4; ++ks) {
    short8 a8[2], b8[4];
#pragma unroll
    for (int i = 0; i < 2; ++i) {
      int row = (wr * 2 + i) * 16 + cc;
      a8[i] = *(const short8*)(As + row * 128 + (((ks * 4 + q) ^ cc) << 3));
    }
#pragma unroll
    for (int jt = 0; jt < 4; ++jt)
      b8[jt] = *(const short8*)(wfp + ((((nc * 8 + wc * 4 + jt) * 4 + ks) * 64 + lane) << 3));
#pragma unroll
    for (int i = 0; i < 2; ++i)
#pragma unroll
      for (int jt = 0; jt < 4; ++jt)
        acc[i][jt] = __builtin_amdgcn_mfma_f32_16x16x32_bf16(a8[i], b8[jt], acc[i][jt], 0, 0, 0);
  }
#pragma unroll
  for (int jt = 0; jt < 4; ++jt) {
    int colG = nc * 128 + (wc * 4 + jt) * 16 + cc;
    float bv = biasq[colG];
#pragma unroll
    for (int i = 0; i < 2; ++i)
#pragma unroll
      for (int r = 0; r < 4; ++r) {
        int row = (wr * 2 + i) * 16 + q * 4 + r;
        C[(size_t)(row0 + row) * 384 + colG] = f2bf(acc[i][jt][r] + bv);
      }
  }
}

// ---------------------------------------------------------------------------
// MFMA GEMM: out[16384x128] = bf16(agg) @ wop + ori_x. M=64 blocks, no spill.
// ---------------------------------------------------------------------------
__global__ __launch_bounds__(256, 4) void gemm_out(
    const float* __restrict__ A, const short* __restrict__ wop,
    const float* __restrict__ R, float* __restrict__ C)
{
  __shared__ short As[64 * 128];
  const int tid = threadIdx.x;
  const int lane = tid & 63, w = tid >> 6;
  const int wr = w >> 1, wc = w & 1;
  const int q = lane >> 4, cc = lane & 15;
  const int row0 = blockIdx.x * 64;
#pragma unroll
  for (int it = 0; it < 4; ++it) {
    int e = tid + it * 256;
    int row = e >> 4, cg = e & 15;
    const float* src = A + (size_t)(row0 + row) * 128 + cg * 8;
    float4 f0 = *(const float4*)src, f1 = *(const float4*)(src + 4);
    short8 v;
    v[0] = f2bf(f0.x); v[1] = f2bf(f0.y); v[2] = f2bf(f0.z); v[3] = f2bf(f0.w);
    v[4] = f2bf(f1.x); v[5] = f2bf(f1.y); v[6] = f2bf(f1.z); v[7] = f2bf(f1.w);
    *(short8*)(As + row * 128 + ((cg ^ (row & 15)) << 3)) = v;
  }
  __syncthreads();
  floatx4 acc[2][4];
#pragma unroll
  for (int i = 0; i < 2; ++i)
#pragma unroll
    for (int jt = 0; jt < 4; ++jt) acc[i][jt] = (floatx4){0.f, 0.f, 0.f, 0.f};
#pragma unroll
  for (int ks = 0; ks < 4; ++ks) {
    short8 a8[2], b8[4];
#pragma unroll
    for (int i = 0; i < 2; ++i) {
      int row = (wr * 2 + i) * 16 + cc;
      a8[i] = *(const short8*)(As + row * 128 + (((ks * 4 + q) ^ cc) << 3));
    }
#pragma unroll
    for (int jt = 0; jt < 4; ++jt)
      b8[jt] = *(const short8*)(wop + ((((wc * 4 + jt) * 4 + ks) * 64 + lane) << 3));
#pragma unroll
    for (int i = 0; i < 2; ++i)
#pragma unroll
      for (int jt = 0; jt < 4; ++jt)
        acc[i][jt] = __builtin_amdgcn_mfma_f32_16x16x32_bf16(a8[i], b8[jt], acc[i][jt], 0, 0, 0);
  }
#pragma unroll
  for (int jt = 0; jt < 4; ++jt) {
    int col = (wc * 4 + jt) * 16 + cc;
#pragma unroll
    for (int i = 0; i < 2; ++i)
#pragma unroll
      for (int r = 0; r < 4; ++r) {
        int row = (wr * 2 + i) * 16 + q * 4 + r;
        size_t o = (size_t)(row0 + row) * 128 + col;
        C[o] = acc[i][jt][r] + R[o];
      }
  }
}

// ---------------------------------------------------------------------------
// Fused MFMA attention: 4 points/block (M=64), 4 waves each 32x64, 64-col AH
// chunks, double-buffered t1. Small tiles keep live regs ~150 (no spill) at
// 3 blocks/CU (launch_bounds (256,3)). XCD-affinity: batch = blockIdx.x & 7.
// LDS ~34 KB.
// ---------------------------------------------------------------------------
__global__ __launch_bounds__(256, 3) void fused_attn(
    const float* __restrict__ pos, const short* __restrict__ qkv,
    const int* __restrict__ knn_idx,
    const float* __restrict__ pos_w1,
    const short* __restrict__ w1p, const short* __restrict__ w2p,
    const short* __restrict__ pw2p,
    const float* __restrict__ t1sc, const float* __restrict__ t1bi,
    const float* __restrict__ phsc, const float* __restrict__ phbi,
    const float* __restrict__ attn_b2,
    float* __restrict__ agg)
{
  __shared__ short a_s[64 * 128];       // 16 KB, XOR swizzle on row&15
  __shared__ short t1_s[2][64 * 64];    // 16 KB, XOR swizzle on row&7
  __shared__ short q_ss[4 * 128];       // 1 KB bf16 q rows
  __shared__ float relp_s[64 * 4];
  __shared__ int   nbr_s[64];

  const int tid = threadIdx.x;
  const int lane = tid & 63, w = tid >> 6;
  const int wr = w >> 1, wc = w & 1;
  const int q = lane >> 4, cc = lane & 15;
  // XCD-affinity swizzle: all blocks of one batch land on one XCD (mod-8 rr).
  const int bb = blockIdx.x & 7;
  const int gp0 = bb * NN + (blockIdx.x >> 3) * 4;   // 4 points/block

  if (tid < 64) nbr_s[tid] = knn_idx[(size_t)gp0 * KNN + tid];
  if (tid >= 64 && tid < 128) {  // stage q rows (bf16)
    int e = tid - 64;
    int p = e >> 4, seg = e & 15;
    *(short8*)(q_ss + p * 128 + seg * 8) =
        *(const short8*)(qkv + (size_t)(gp0 + p) * 384 + seg * 8);
  }
  __syncthreads();
  if (tid < 64) {
    int p = tid >> 4;
    int j = nbr_s[tid];
    const float* pa = pos + (size_t)(gp0 + p) * 3;
    const float* pj = pos + ((size_t)bb * NN + j) * 3;
    relp_s[tid * 4 + 0] = pa[0] - pj[0];
    relp_s[tid * 4 + 1] = pa[1] - pj[1];
    relp_s[tid * 4 + 2] = pa[2] - pj[2];
  }
  __syncthreads();

  // ph = relu(bn(relp @ pos_w1 + b1)) -> t1_s[0] (64 rows x 64 cols)
#pragma unroll
  for (int r2 = 0; r2 < 16; ++r2) {
    int e = tid + r2 * 256;
    int row = e >> 6, c = e & 63;
    float lin = relp_s[row * 4] * pos_w1[c] + relp_s[row * 4 + 1] * pos_w1[64 + c]
              + relp_s[row * 4 + 2] * pos_w1[128 + c];
    t1_s[0][row * 64 + (((c >> 3) ^ (row & 7)) << 3) + (c & 7)] =
        f2bf(fmaxf(lin * phsc[c] + phbi[c], 0.0f));
  }
  __syncthreads();

  // pe = ph @ pos_w2 (pos_b2 pre-folded into qkv q/v cols)
  floatx4 pe[2][4];
#pragma unroll
  for (int i = 0; i < 2; ++i)
#pragma unroll
    for (int jt = 0; jt < 4; ++jt) pe[i][jt] = (floatx4){0.f, 0.f, 0.f, 0.f};
#pragma unroll
  for (int ks = 0; ks < 2; ++ks) {
    short8 a8[2];
#pragma unroll
    for (int i = 0; i < 2; ++i) {
      int row = (wr * 2 + i) * 16 + cc;
      a8[i] = *(const short8*)(t1_s[0] + row * 64 + (((ks * 4 + q) ^ (row & 7)) << 3));
    }
#pragma unroll
    for (int jt = 0; jt < 4; ++jt) {
      short8 b8 = *(const short8*)(pw2p + ((((wc * 4 + jt) * 2 + ks) * 64 + lane) << 3));
#pragma unroll
      for (int i = 0; i < 2; ++i)
        pe[i][jt] = __builtin_amdgcn_mfma_f32_16x16x32_bf16(a8[i], b8, pe[i][jt], 0, 0, 0);
    }
  }

  // combine: a = q - k_g + pe -> a_s ; vpe = v_g + pe -> packed bf16 regs
  unsigned vpe_pk[2][4][2];
#pragma unroll
  for (int i = 0; i < 2; ++i) {
    int rt = wr * 2 + i;                 // row tile == local point index
#pragma unroll
    for (int jt = 0; jt < 4; ++jt) {
      int col = (wc * 4 + jt) * 16 + cc;
      float qv = bf2f(q_ss[rt * 128 + col]);
      short vb[4];
#pragma unroll
      for (int r = 0; r < 4; ++r) {
        int row = rt * 16 + q * 4 + r;
        const short* kv = qkv + ((size_t)bb * NN + nbr_s[row]) * 384;
        float pev = pe[i][jt][r];
        a_s[row * 128 + (((col >> 3) ^ (row & 15)) << 3) + (col & 7)] =
            f2bf(qv - bf2f(kv[128 + col]) + pev);
        vb[r] = f2bf(bf2f(kv[256 + col]) + pev);
      }
      vpe_pk[i][jt][0] = ((unsigned)(unsigned short)vb[1] << 16) | (unsigned short)vb[0];
      vpe_pk[i][jt][1] = ((unsigned)(unsigned short)vb[3] << 16) | (unsigned short)vb[2];
    }
  }
  __syncthreads();   // a_s fully built; pe reads of t1_s[0] complete

  floatx4 hacc[2][4];
#pragma unroll
  for (int i = 0; i < 2; ++i)
#pragma unroll
    for (int jt = 0; jt < 4; ++jt) hacc[i][jt] = (floatx4){0.f, 0.f, 0.f, 0.f};

  for (int ch = 0; ch < 8; ++ch) {
    short* t1b = t1_s[ch & 1];
    // GEMM1: tacc = a @ w1[:, ch*64 : +64]  (wave covers 32 rows x 32 cols)
    floatx4 tacc[2][2];
#pragma unroll
    for (int i = 0; i < 2; ++i)
#pragma unroll
      for (int jt = 0; jt < 2; ++jt) tacc[i][jt] = (floatx4){0.f, 0.f, 0.f, 0.f};
#pragma unroll
    for (int ks = 0; ks < 4; ++ks) {
      short8 a8[2], b8[2];
#pragma unroll
      for (int i = 0; i < 2; ++i) {
        int row = (wr * 2 + i) * 16 + cc;
        a8[i] = *(const short8*)(a_s + row * 128 + (((ks * 4 + q) ^ cc) << 3));
      }
#pragma unroll
      for (int jt = 0; jt < 2; ++jt)
        b8[jt] = *(const short8*)(w1p + ((((ch * 4 + wc * 2 + jt) * 4 + ks) * 64 + lane) << 3));
#pragma unroll
      for (int i = 0; i < 2; ++i)
#pragma unroll
        for (int jt = 0; jt < 2; ++jt)
          tacc[i][jt] = __builtin_amdgcn_mfma_f32_16x16x32_bf16(a8[i], b8[jt], tacc[i][jt], 0, 0, 0);
    }
    // bn/relu -> t1b (64-col, swizzled)
#pragma unroll
    for (int jt = 0; jt < 2; ++jt) {
      int colL = (wc * 2 + jt) * 16 + cc;
      int colG = ch * 64 + colL;
      float sc = t1sc[colG], bi = t1bi[colG];
#pragma unroll
      for (int i = 0; i < 2; ++i)
#pragma unroll
        for (int r = 0; r < 4; ++r) {
          int row = (wr * 2 + i) * 16 + q * 4 + r;
          t1b[row * 64 + (((colL >> 3) ^ (row & 7)) << 3) + (colL & 7)] =
              f2bf(fmaxf(tacc[i][jt][r] * sc + bi, 0.0f));
        }
    }
    __syncthreads();   // t1b visible; ping-pong protects in-flight reads
    // GEMM2: hacc += t1 @ w2[ch*64 : +64, :]
#pragma unroll
    for (int ks = 0; ks < 2; ++ks) {
      short8 a8[2], b8[4];
#pragma unroll
      for (int i = 0; i < 2; ++i) {
        int row = (wr * 2 + i) * 16 + cc;
        a8[i] = *(const short8*)(t1b + row * 64 + (((ks * 4 + q) ^ (row & 7)) << 3));
      }
#pragma unroll
      for (int jt = 0; jt < 4; ++jt)
        b8[jt] = *(const short8*)(w2p + ((((ch * 8 + wc * 4 + jt) * 2 + ks) * 64 + lane) << 3));
#pragma unroll
      for (int i = 0; i < 2; ++i)
#pragma unroll
        for (int jt = 0; jt < 4; ++jt)
          hacc[i][jt] = __builtin_amdgcn_mfma_f32_16x16x32_bf16(a8[i], b8[jt], hacc[i][jt], 0, 0, 0);
    }
  }

  // softmax over the 16 neighbors per (point, channel) + aggregate
#pragma unroll
  for (int i = 0; i < 2; ++i) {
    int rt = wr * 2 + i;
#pragma unroll
    for (int jt = 0; jt < 4; ++jt) {
      int col = (wc * 4 + jt) * 16 + cc;
      float b2v = attn_b2[col];
      float v0[4], mx = -3.4e38f;
#pragma unroll
      for (int r = 0; r < 4; ++r) {
        v0[r] = (hacc[i][jt][r] + b2v) * SCALE;
        mx = fmaxf(mx, v0[r]);
      }
      mx = fmaxf(mx, __shfl_xor(mx, 16));
      mx = fmaxf(mx, __shfl_xor(mx, 32));
      float ex[4], sum = 0.f;
#pragma unroll
      for (int r = 0; r < 4; ++r) { ex[r] = __expf(v0[r] - mx); sum += ex[r]; }
      sum += __shfl_xor(sum, 16);
      sum += __shfl_xor(sum, 32);
      float inv = 1.0f / sum;
      float vv[4];
      vv[0] = bf2f((short)(vpe_pk[i][jt][0] & 0xffff));
      vv[1] = bf2f((short)(vpe_pk[i][jt][0] >> 16));
      vv[2] = bf2f((short)(vpe_pk[i][jt][1] & 0xffff));
      vv[3] = bf2f((short)(vpe_pk[i][jt][1] >> 16));
      float part = 0.f;
#pragma unroll
      for (int r = 0; r < 4; ++r) part += ex[r] * vv[r];
      part += __shfl_xor(part, 16);
      part += __shfl_xor(part, 32);
      if (q == 0) agg[(size_t)(gp0 + rt) * DIM + col] = part * inv;
    }
  }
}

extern "C" void kernel_launch(void* const* d_in, const int* in_sizes, int n_in,
                              void* d_out, int out_size, void* d_ws, size_t ws_size,
                              hipStream_t stream)
{
  const float* ori_x    = (const float*)d_in[0];
  const float* pos      = (const float*)d_in[1];
  const float* w_in     = (const float*)d_in[2];
  const float* w_qkv    = (const float*)d_in[3];
  const float* w_out    = (const float*)d_in[4];
  const float* pos_w1   = (const float*)d_in[5];
  const float* pos_b1   = (const float*)d_in[6];
  const float* pos_bn_g = (const float*)d_in[7];
  const float* pos_bn_b = (const float*)d_in[8];
  const float* pos_bn_m = (const float*)d_in[9];
  const float* pos_bn_v = (const float*)d_in[10];
  const float* pos_w2   = (const float*)d_in[11];
  const float* pos_b2   = (const float*)d_in[12];
  const float* attn_w1  = (const float*)d_in[13];
  const float* attn_b1  = (const float*)d_in[14];
  const float* attn_bn_g = (const float*)d_in[15];
  const float* attn_bn_b = (const float*)d_in[16];
  const float* attn_bn_m = (const float*)d_in[17];
  const float* attn_bn_v = (const float*)d_in[18];
  const float* attn_w2  = (const float*)d_in[19];
  const float* attn_b2  = (const float*)d_in[20];
  float* out = (float*)d_out;

  float* agg  = (float*)d_ws;                          // [NPTS*128] f32; Wf aliases head
  float* Wf   = agg;                                   // [128*384] (consumed by pack)
  short* qkvb = (short*)(agg + (size_t)NPTS * DIM);    // [NPTS*384] bf16
  int*   idx  = (int*)(qkvb + (size_t)NPTS * 3 * DIM); // [NPTS*16]
  short* w1p  = (short*)(idx + (size_t)NPTS * KNN);
  short* w2p  = w1p + 65536;
  short* pw2p = w2p + 65536;
  short* wfp  = pw2p + 8192;
  short* wop  = wfp + 49152;
  float* biasq = (float*)(wop + 16384);
  float* t1sc = biasq + 384;
  float* t1bi = t1sc + 512;
  float* phsc = t1bi + 512;
  float* phbi = phsc + 64;

  gemm_f32<<<dim3(2, 6), 256, 0, stream>>>(w_in, w_qkv, Wf, 128, 384, 128);
  pack_weights<<<807, 256, 0, stream>>>(attn_w1, attn_w2, pos_w2, Wf, w_out,
      attn_b1, attn_bn_g, attn_bn_b, attn_bn_m, attn_bn_v,
      pos_b1, pos_bn_g, pos_bn_b, pos_bn_m, pos_bn_v, pos_b2,
      w1p, w2p, pw2p, wfp, wop, biasq, t1sc, t1bi, phsc, phbi);
  gemm_in<<<dim3(NPTS / 64, 3), 256, 0, stream>>>(ori_x, wfp, biasq, qkvb);
  knn_kernel<<<NPTS / 4, 256, 0, stream>>>(pos, idx);
  fused_attn<<<NPTS / 4, 256, 0, stream>>>(pos, qkvb, idx, pos_w1,
      w1p, w2p, pw2p, t1sc, t1bi, phsc, phbi, attn_b2, agg);
  gemm_out<<<NPTS / 64, 256, 0, stream>>>(agg, wop, ori_x, out);
}

// Round 7
// 399.683 us; speedup vs baseline: 1.4116x; 1.1286x over previous
//
#include <hip/hip_runtime.h>

#define EPS 1e-5f

constexpr int NB   = 8;
constexpr int NN   = 2048;
constexpr int DIM  = 128;
constexpr int KNN  = 16;
constexpr int AH   = 512;
constexpr int NPTS = NB * NN;
constexpr float SCALE = 0.08838834764831845f; // 1/sqrt(128)

typedef __attribute__((ext_vector_type(8))) short short8;
typedef __attribute__((ext_vector_type(4))) float floatx4;

__device__ __forceinline__ short f2bf(float f) {
  union { float f; unsigned u; } a; a.f = f;
  unsigned u = a.u;
  unsigned r = (u + 0x7fffu + ((u >> 16) & 1u)) >> 16;  // RNE
  return (short)r;
}
__device__ __forceinline__ float bf2f(short s) {
  union { unsigned u; float f; } a; a.u = ((unsigned)(unsigned short)s) << 16;
  return a.f;
}

// ---------------------------------------------------------------------------
// fp32 tiled GEMM (only Wf = w_in @ w_qkv, tiny). 64x64 tile.
// ---------------------------------------------------------------------------
__global__ __launch_bounds__(256) void gemm_f32(
    const float* __restrict__ A, const float* __restrict__ W,
    float* __restrict__ C, int M, int N, int K)
{
  __shared__ float As[64][33];
  __shared__ float Ws[32][65];
  const int bm = blockIdx.x * 64, bn = blockIdx.y * 64;
  const int tid = threadIdx.x;
  const int tx = tid & 15, ty = tid >> 4;
  float acc[4][4] = {};
  for (int k0 = 0; k0 < K; k0 += 32) {
#pragma unroll
    for (int i = 0; i < 8; ++i) {
      int e = tid + i * 256;
      As[e >> 5][e & 31] = A[(size_t)(bm + (e >> 5)) * K + k0 + (e & 31)];
    }
#pragma unroll
    for (int i = 0; i < 8; ++i) {
      int e = tid + i * 256;
      Ws[e >> 6][e & 63] = W[(size_t)(k0 + (e >> 6)) * N + bn + (e & 63)];
    }
    __syncthreads();
#pragma unroll
    for (int kk = 0; kk < 32; ++kk) {
      float a[4], w[4];
#pragma unroll
      for (int i = 0; i < 4; ++i) a[i] = As[ty * 4 + i][kk];
#pragma unroll
      for (int j = 0; j < 4; ++j) w[j] = Ws[kk][tx * 4 + j];
#pragma unroll
      for (int i = 0; i < 4; ++i)
#pragma unroll
        for (int j = 0; j < 4; ++j)
          acc[i][j] += a[i] * w[j];
    }
    __syncthreads();
  }
#pragma unroll
  for (int i = 0; i < 4; ++i)
#pragma unroll
    for (int j = 0; j < 4; ++j)
      C[(size_t)(bm + ty * 4 + i) * N + bn + tx * 4 + j] = acc[i][j];
}

// ---------------------------------------------------------------------------
// pos -> SoA pos_t[b][3][NN] for coalesced KNN loads.
// ---------------------------------------------------------------------------
__global__ __launch_bounds__(256) void transpose_pos(
    const float* __restrict__ pos, float* __restrict__ pos_t)
{
  int t = blockIdx.x * 256 + threadIdx.x;
  if (t < NPTS * 3) {
    int p = t / 3, d = t - p * 3;
    int b = p >> 11, n = p & (NN - 1);
    pos_t[((size_t)b * 3 + d) * NN + n] = pos[t];
  }
}

// ---------------------------------------------------------------------------
// KNN: one wave per point; 32 distances/lane in regs (SoA coalesced loads);
// 16 butterfly-argmin rounds; lowest-index tie-break. No LDS/barriers.
// ---------------------------------------------------------------------------
__global__ __launch_bounds__(256) void knn_kernel(
    const float* __restrict__ pos_t, int* __restrict__ idx_out)
{
  const int tid = threadIdx.x;
  const int lane = tid & 63;
  const int p = blockIdx.x * 4 + (tid >> 6);
  const int b = p >> 11, i = p & (NN - 1);
  const float* px = pos_t + (size_t)b * 3 * NN;
  const float* py = px + NN;
  const float* pz = py + NN;
  const float xi = px[i], yi = py[i], zi = pz[i];
  const float sqi = xi * xi + yi * yi + zi * zi;
  float v[32];
#pragma unroll
  for (int t = 0; t < 32; ++t) {
    int j = t * 64 + lane;
    float xj = px[j], yj = py[j], zj = pz[j];
    float sqj = xj * xj + yj * yj + zj * zj;
    float dot = xi * xj + yi * yj + zi * zj;
    v[t] = sqi + sqj - 2.0f * dot;
  }
  for (int s = 0; s < KNN; ++s) {
    float bv = 3.4e38f; int bj = 1 << 30;
#pragma unroll
    for (int t = 0; t < 32; ++t) {
      if (v[t] < bv) { bv = v[t]; bj = t * 64 + lane; }
    }
#pragma unroll
    for (int m = 1; m < 64; m <<= 1) {
      float ov = __shfl_xor(bv, m);
      int   oj = __shfl_xor(bj, m);
      if (ov < bv || (ov == bv && oj < bj)) { bv = ov; bj = oj; }
    }
    if (lane == 0) idx_out[(size_t)p * KNN + s] = bj;
#pragma unroll
    for (int t = 0; t < 32; ++t)
      if (bj == t * 64 + lane) v[t] = 3.4e38f;
  }
}

// ---------------------------------------------------------------------------
// Pack weights into bf16 B-fragment layouts (frag f at [f*512 + lane*8 + j],
// value = W[k = ks*32 + q*8 + j][n]) + folded BN + biases.
// ---------------------------------------------------------------------------
__global__ __launch_bounds__(256) void pack_weights(
    const float* __restrict__ attn_w1, const float* __restrict__ attn_w2,
    const float* __restrict__ pos_w2, const float* __restrict__ Wf,
    const float* __restrict__ w_out,
    const float* __restrict__ attn_b1, const float* __restrict__ abn_g,
    const float* __restrict__ abn_b, const float* __restrict__ abn_m,
    const float* __restrict__ abn_v,
    const float* __restrict__ pos_b1, const float* __restrict__ pbn_g,
    const float* __restrict__ pbn_b, const float* __restrict__ pbn_m,
    const float* __restrict__ pbn_v, const float* __restrict__ pos_b2,
    short* __restrict__ w1p, short* __restrict__ w2p, short* __restrict__ pw2p,
    short* __restrict__ wfp, short* __restrict__ wop,
    float* __restrict__ biasq,
    float* __restrict__ t1sc, float* __restrict__ t1bi,
    float* __restrict__ phsc, float* __restrict__ phbi)
{
  int t = blockIdx.x * 256 + threadIdx.x;
  if (t < 65536) {                       // w1p: [128x512], 8 chunks of 64 cols
    int j = t & 7, lane = (t >> 3) & 63, ks = (t >> 9) & 3, nt = (t >> 11) & 3, ch = t >> 13;
    int q = lane >> 4, cc = lane & 15;
    int k = ks * 32 + q * 8 + j, n = ch * 64 + nt * 16 + cc;
    w1p[t] = f2bf(attn_w1[(size_t)k * AH + n]);
  } else if (t < 131072) {               // w2p: [512x128], 8 chunks of 64 rows
    int e = t - 65536;
    int j = e & 7, lane = (e >> 3) & 63, ks = (e >> 9) & 1, nt = (e >> 10) & 7, ch = e >> 13;
    int q = lane >> 4, cc = lane & 15;
    int k = ch * 64 + ks * 32 + q * 8 + j, n = nt * 16 + cc;
    w2p[e] = f2bf(attn_w2[(size_t)k * DIM + n]);
  } else if (t < 139264) {               // pw2p: pos_w2 [64x128]
    int e = t - 131072;
    int j = e & 7, lane = (e >> 3) & 63, ks = (e >> 9) & 1, nt = e >> 10;
    int q = lane >> 4, cc = lane & 15;
    int k = ks * 32 + q * 8 + j, n = nt * 16 + cc;
    pw2p[e] = f2bf(pos_w2[(size_t)k * DIM + n]);
  } else if (t < 188416) {               // wfp: Wf [128x384], 3 col-chunks
    int e = t - 139264;
    int j = e & 7, lane = (e >> 3) & 63, ks = (e >> 9) & 3, nt = (e >> 11) & 7, nc = e >> 14;
    int q = lane >> 4, cc = lane & 15;
    int k = ks * 32 + q * 8 + j, n = nc * 128 + nt * 16 + cc;
    wfp[e] = f2bf(Wf[(size_t)k * 384 + n]);
  } else if (t < 204800) {               // wop: w_out [128x128]
    int e = t - 188416;
    int j = e & 7, lane = (e >> 3) & 63, ks = (e >> 9) & 3, nt = (e >> 11) & 7;
    int q = lane >> 4, cc = lane & 15;
    int k = ks * 32 + q * 8 + j, n = nt * 16 + cc;
    wop[e] = f2bf(w_out[(size_t)k * DIM + n]);
  } else if (t < 205184) {               // biasq[384]: pos_b2 into q,v cols
    int c = t - 204800;
    biasq[c] = (c < 128) ? pos_b2[c] : ((c < 256) ? 0.0f : pos_b2[c - 256]);
  } else if (t < 205696) {
    int c = t - 205184;
    t1sc[c] = abn_g[c] * rsqrtf(abn_v[c] + EPS);
  } else if (t < 206208) {
    int c = t - 205696;
    float sc = abn_g[c] * rsqrtf(abn_v[c] + EPS);
    t1bi[c] = (attn_b1[c] - abn_m[c]) * sc + abn_b[c];
  } else if (t < 206272) {
    int c = t - 206208;
    phsc[c] = pbn_g[c] * rsqrtf(pbn_v[c] + EPS);
  } else if (t < 206336) {
    int c = t - 206272;
    float sc = pbn_g[c] * rsqrtf(pbn_v[c] + EPS);
    phbi[c] = (pos_b1[c] - pbn_m[c]) * sc + pbn_b[c];
  }
}

// ---------------------------------------------------------------------------
// MFMA GEMM: qkv[16384x384] (bf16 out) = bf16(ori_x) @ wfp + biasq.
// M=64 blocks; 3 col-chunks looped inside (A staged once).
// ---------------------------------------------------------------------------
__global__ __launch_bounds__(256, 4) void gemm_in(
    const float* __restrict__ A, const short* __restrict__ wfp,
    const float* __restrict__ biasq, short* __restrict__ C)
{
  __shared__ short As[64 * 128];
  const int tid = threadIdx.x;
  const int lane = tid & 63, w = tid >> 6;
  const int wr = w >> 1, wc = w & 1;
  const int q = lane >> 4, cc = lane & 15;
  const int row0 = blockIdx.x * 64;
#pragma unroll
  for (int it = 0; it < 4; ++it) {
    int e = tid + it * 256;
    int row = e >> 4, cg = e & 15;
    const float* src = A + (size_t)(row0 + row) * 128 + cg * 8;
    float4 f0 = *(const float4*)src, f1 = *(const float4*)(src + 4);
    short8 v;
    v[0] = f2bf(f0.x); v[1] = f2bf(f0.y); v[2] = f2bf(f0.z); v[3] = f2bf(f0.w);
    v[4] = f2bf(f1.x); v[5] = f2bf(f1.y); v[6] = f2bf(f1.z); v[7] = f2bf(f1.w);
    *(short8*)(As + row * 128 + ((cg ^ (row & 15)) << 3)) = v;
  }
  __syncthreads();
  for (int nc = 0; nc < 3; ++nc) {
    floatx4 acc[2][4];
#pragma unroll
    for (int i = 0; i < 2; ++i)
#pragma unroll
      for (int jt = 0; jt < 4; ++jt) acc[i][jt] = (floatx4){0.f, 0.f, 0.f, 0.f};
#pragma unroll
    for (int ks = 0; ks < 4; ++ks) {
      short8 a8[2], b8[4];
#pragma unroll
      for (int i = 0; i < 2; ++i) {
        int row = (wr * 2 + i) * 16 + cc;
        a8[i] = *(const short8*)(As + row * 128 + (((ks * 4 + q) ^ cc) << 3));
      }
#pragma unroll
      for (int jt = 0; jt < 4; ++jt)
        b8[jt] = *(const short8*)(wfp + ((((nc * 8 + wc * 4 + jt) * 4 + ks) * 64 + lane) << 3));
#pragma unroll
      for (int i = 0; i < 2; ++i)
#pragma unroll
        for (int jt = 0; jt < 4; ++jt)
          acc[i][jt] = __builtin_amdgcn_mfma_f32_16x16x32_bf16(a8[i], b8[jt], acc[i][jt], 0, 0, 0);
    }
#pragma unroll
    for (int jt = 0; jt < 4; ++jt) {
      int colG = nc * 128 + (wc * 4 + jt) * 16 + cc;
      float bv = biasq[colG];
#pragma unroll
      for (int i = 0; i < 2; ++i)
#pragma unroll
        for (int r = 0; r < 4; ++r) {
          int row = (wr * 2 + i) * 16 + q * 4 + r;
          C[(size_t)(row0 + row) * 384 + colG] = f2bf(acc[i][jt][r] + bv);
        }
    }
  }
}

// ---------------------------------------------------------------------------
// MFMA GEMM: out[16384x128] = bf16(agg) @ wop + ori_x. M=64 blocks.
// ---------------------------------------------------------------------------
__global__ __launch_bounds__(256, 4) void gemm_out(
    const float* __restrict__ A, const short* __restrict__ wop,
    const float* __restrict__ R, float* __restrict__ C)
{
  __shared__ short As[64 * 128];
  const int tid = threadIdx.x;
  const int lane = tid & 63, w = tid >> 6;
  const int wr = w >> 1, wc = w & 1;
  const int q = lane >> 4, cc = lane & 15;
  const int row0 = blockIdx.x * 64;
#pragma unroll
  for (int it = 0; it < 4; ++it) {
    int e = tid + it * 256;
    int row = e >> 4, cg = e & 15;
    const float* src = A + (size_t)(row0 + row) * 128 + cg * 8;
    float4 f0 = *(const float4*)src, f1 = *(const float4*)(src + 4);
    short8 v;
    v[0] = f2bf(f0.x); v[1] = f2bf(f0.y); v[2] = f2bf(f0.z); v[3] = f2bf(f0.w);
    v[4] = f2bf(f1.x); v[5] = f2bf(f1.y); v[6] = f2bf(f1.z); v[7] = f2bf(f1.w);
    *(short8*)(As + row * 128 + ((cg ^ (row & 15)) << 3)) = v;
  }
  __syncthreads();
  floatx4 acc[2][4];
#pragma unroll
  for (int i = 0; i < 2; ++i)
#pragma unroll
    for (int jt = 0; jt < 4; ++jt) acc[i][jt] = (floatx4){0.f, 0.f, 0.f, 0.f};
#pragma unroll
  for (int ks = 0; ks < 4; ++ks) {
    short8 a8[2], b8[4];
#pragma unroll
    for (int i = 0; i < 2; ++i) {
      int row = (wr * 2 + i) * 16 + cc;
      a8[i] = *(const short8*)(As + row * 128 + (((ks * 4 + q) ^ cc) << 3));
    }
#pragma unroll
    for (int jt = 0; jt < 4; ++jt)
      b8[jt] = *(const short8*)(wop + ((((wc * 4 + jt) * 4 + ks) * 64 + lane) << 3));
#pragma unroll
    for (int i = 0; i < 2; ++i)
#pragma unroll
      for (int jt = 0; jt < 4; ++jt)
        acc[i][jt] = __builtin_amdgcn_mfma_f32_16x16x32_bf16(a8[i], b8[jt], acc[i][jt], 0, 0, 0);
  }
#pragma unroll
  for (int jt = 0; jt < 4; ++jt) {
    int col = (wc * 4 + jt) * 16 + cc;
#pragma unroll
    for (int i = 0; i < 2; ++i)
#pragma unroll
      for (int r = 0; r < 4; ++r) {
        int row = (wr * 2 + i) * 16 + q * 4 + r;
        size_t o = (size_t)(row0 + row) * 128 + col;
        C[o] = acc[i][jt][r] + R[o];
      }
  }
}

// ---------------------------------------------------------------------------
// Fused MFMA attention: 4 points/block (M=64), 4 waves each 32x64, 64-col AH
// chunks, double-buffered t1. pe staged through a_s (pass A/B) so its 32 acc
// regs never overlap the gather phase -> fits (256,3) without spill.
// LDS ~34 KB -> 3 blocks/CU. XCD-affinity: batch = blockIdx.x & 7.
// ---------------------------------------------------------------------------
__global__ __launch_bounds__(256, 3) void fused_attn(
    const float* __restrict__ pos, const short* __restrict__ qkv,
    const int* __restrict__ knn_idx,
    const float* __restrict__ pos_w1,
    const short* __restrict__ w1p, const short* __restrict__ w2p,
    const short* __restrict__ pw2p,
    const float* __restrict__ t1sc, const float* __restrict__ t1bi,
    const float* __restrict__ phsc, const float* __restrict__ phbi,
    const float* __restrict__ attn_b2,
    float* __restrict__ agg)
{
  __shared__ short a_s[64 * 128];       // 16 KB, XOR swizzle on row&15
  __shared__ short t1_s[2][64 * 64];    // 16 KB, XOR swizzle on row&7
  __shared__ short q_ss[4 * 128];       // 1 KB bf16 q rows
  __shared__ float relp_s[64 * 4];
  __shared__ int   nbr_s[64];

  const int tid = threadIdx.x;
  const int lane = tid & 63, w = tid >> 6;
  const int wr = w >> 1, wc = w & 1;
  const int q = lane >> 4, cc = lane & 15;
  const int bb = blockIdx.x & 7;                     // XCD-affinity swizzle
  const int gp0 = bb * NN + (blockIdx.x >> 3) * 4;   // 4 points/block

  if (tid < 64) nbr_s[tid] = knn_idx[(size_t)gp0 * KNN + tid];
  if (tid >= 64 && tid < 128) {  // stage q rows (bf16)
    int e = tid - 64;
    int p = e >> 4, seg = e & 15;
    *(short8*)(q_ss + p * 128 + seg * 8) =
        *(const short8*)(qkv + (size_t)(gp0 + p) * 384 + seg * 8);
  }
  __syncthreads();
  if (tid < 64) {
    int p = tid >> 4;
    int j = nbr_s[tid];
    const float* pa = pos + (size_t)(gp0 + p) * 3;
    const float* pj = pos + ((size_t)bb * NN + j) * 3;
    relp_s[tid * 4 + 0] = pa[0] - pj[0];
    relp_s[tid * 4 + 1] = pa[1] - pj[1];
    relp_s[tid * 4 + 2] = pa[2] - pj[2];
  }
  __syncthreads();

  // ph = relu(bn(relp @ pos_w1 + b1)) -> t1_s[0] (64 rows x 64 cols)
#pragma unroll
  for (int r2 = 0; r2 < 16; ++r2) {
    int e = tid + r2 * 256;
    int row = e >> 6, c = e & 63;
    float lin = relp_s[row * 4] * pos_w1[c] + relp_s[row * 4 + 1] * pos_w1[64 + c]
              + relp_s[row * 4 + 2] * pos_w1[128 + c];
    t1_s[0][row * 64 + (((c >> 3) ^ (row & 7)) << 3) + (c & 7)] =
        f2bf(fmaxf(lin * phsc[c] + phbi[c], 0.0f));
  }
  __syncthreads();

  // --- Pass A: pe = ph @ pos_w2 -> bf16 into a_s (pe regs die here) ---
  {
    floatx4 pe[2][4];
#pragma unroll
    for (int i = 0; i < 2; ++i)
#pragma unroll
      for (int jt = 0; jt < 4; ++jt) pe[i][jt] = (floatx4){0.f, 0.f, 0.f, 0.f};
#pragma unroll
    for (int ks = 0; ks < 2; ++ks) {
      short8 a8[2];
#pragma unroll
      for (int i = 0; i < 2; ++i) {
        int row = (wr * 2 + i) * 16 + cc;
        a8[i] = *(const short8*)(t1_s[0] + row * 64 + (((ks * 4 + q) ^ (row & 7)) << 3));
      }
#pragma unroll
      for (int jt = 0; jt < 4; ++jt) {
        short8 b8 = *(const short8*)(pw2p + ((((wc * 4 + jt) * 2 + ks) * 64 + lane) << 3));
#pragma unroll
        for (int i = 0; i < 2; ++i)
          pe[i][jt] = __builtin_amdgcn_mfma_f32_16x16x32_bf16(a8[i], b8, pe[i][jt], 0, 0, 0);
      }
    }
#pragma unroll
    for (int i = 0; i < 2; ++i) {
      int rt = wr * 2 + i;
#pragma unroll
      for (int jt = 0; jt < 4; ++jt) {
        int col = (wc * 4 + jt) * 16 + cc;
#pragma unroll
        for (int r = 0; r < 4; ++r) {
          int row = rt * 16 + q * 4 + r;
          a_s[row * 128 + (((col >> 3) ^ (row & 15)) << 3) + (col & 7)] =
              f2bf(pe[i][jt][r]);
        }
      }
    }
  }
  // No barrier: pass B reads exactly the slots this thread wrote.

  // --- Pass B: gather k/v; a = q - k + pe (in place); vpe -> packed regs ---
  unsigned vpe_pk[2][4][2];
#pragma unroll
  for (int i = 0; i < 2; ++i) {
    int rt = wr * 2 + i;
#pragma unroll
    for (int jt = 0; jt < 4; ++jt) {
      int col = (wc * 4 + jt) * 16 + cc;
      float qv = bf2f(q_ss[rt * 128 + col]);
      short vb[4];
#pragma unroll
      for (int r = 0; r < 4; ++r) {
        int row = rt * 16 + q * 4 + r;
        const short* kv = qkv + ((size_t)bb * NN + nbr_s[row]) * 384;
        int slot = row * 128 + (((col >> 3) ^ (row & 15)) << 3) + (col & 7);
        float pev = bf2f(a_s[slot]);
        a_s[slot] = f2bf(qv - bf2f(kv[128 + col]) + pev);
        vb[r] = f2bf(bf2f(kv[256 + col]) + pev);
      }
      vpe_pk[i][jt][0] = ((unsigned)(unsigned short)vb[1] << 16) | (unsigned short)vb[0];
      vpe_pk[i][jt][1] = ((unsigned)(unsigned short)vb[3] << 16) | (unsigned short)vb[2];
    }
  }
  __syncthreads();   // a_s fully built; pass-A reads of t1_s[0] complete

  floatx4 hacc[2][4];
#pragma unroll
  for (int i = 0; i < 2; ++i)
#pragma unroll
    for (int jt = 0; jt < 4; ++jt) hacc[i][jt] = (floatx4){0.f, 0.f, 0.f, 0.f};

  for (int ch = 0; ch < 8; ++ch) {
    short* t1b = t1_s[ch & 1];
    // GEMM1: tacc = a @ w1[:, ch*64 : +64]  (wave covers 32 rows x 32 cols)
    floatx4 tacc[2][2];
#pragma unroll
    for (int i = 0; i < 2; ++i)
#pragma unroll
      for (int jt = 0; jt < 2; ++jt) tacc[i][jt] = (floatx4){0.f, 0.f, 0.f, 0.f};
#pragma unroll
    for (int ks = 0; ks < 4; ++ks) {
      short8 a8[2], b8[2];
#pragma unroll
      for (int i = 0; i < 2; ++i) {
        int row = (wr * 2 + i) * 16 + cc;
        a8[i] = *(const short8*)(a_s + row * 128 + (((ks * 4 + q) ^ cc) << 3));
      }
#pragma unroll
      for (int jt = 0; jt < 2; ++jt)
        b8[jt] = *(const short8*)(w1p + ((((ch * 4 + wc * 2 + jt) * 4 + ks) * 64 + lane) << 3));
#pragma unroll
      for (int i = 0; i < 2; ++i)
#pragma unroll
        for (int jt = 0; jt < 2; ++jt)
          tacc[i][jt] = __builtin_amdgcn_mfma_f32_16x16x32_bf16(a8[i], b8[jt], tacc[i][jt], 0, 0, 0);
    }
    // bn/relu -> t1b (64-col, swizzled)
#pragma unroll
    for (int jt = 0; jt < 2; ++jt) {
      int colL = (wc * 2 + jt) * 16 + cc;
      int colG = ch * 64 + colL;
      float sc = t1sc[colG], bi = t1bi[colG];
#pragma unroll
      for (int i = 0; i < 2; ++i)
#pragma unroll
        for (int r = 0; r < 4; ++r) {
          int row = (wr * 2 + i) * 16 + q * 4 + r;
          t1b[row * 64 + (((colL >> 3) ^ (row & 7)) << 3) + (colL & 7)] =
              f2bf(fmaxf(tacc[i][jt][r] * sc + bi, 0.0f));
        }
    }
    __syncthreads();   // t1b visible; ping-pong protects in-flight reads
    // GEMM2: hacc += t1 @ w2[ch*64 : +64, :]
#pragma unroll
    for (int ks = 0; ks < 2; ++ks) {
      short8 a8[2], b8[4];
#pragma unroll
      for (int i = 0; i < 2; ++i) {
        int row = (wr * 2 + i) * 16 + cc;
        a8[i] = *(const short8*)(t1b + row * 64 + (((ks * 4 + q) ^ (row & 7)) << 3));
      }
#pragma unroll
      for (int jt = 0; jt < 4; ++jt)
        b8[jt] = *(const short8*)(w2p + ((((ch * 8 + wc * 4 + jt) * 2 + ks) * 64 + lane) << 3));
#pragma unroll
      for (int i = 0; i < 2; ++i)
#pragma unroll
        for (int jt = 0; jt < 4; ++jt)
          hacc[i][jt] = __builtin_amdgcn_mfma_f32_16x16x32_bf16(a8[i], b8[jt], hacc[i][jt], 0, 0, 0);
    }
  }

  // softmax over the 16 neighbors per (point, channel) + aggregate
#pragma unroll
  for (int i = 0; i < 2; ++i) {
    int rt = wr * 2 + i;
#pragma unroll
    for (int jt = 0; jt < 4; ++jt) {
      int col = (wc * 4 + jt) * 16 + cc;
      float b2v = attn_b2[col];
      float v0[4], mx = -3.4e38f;
#pragma unroll
      for (int r = 0; r < 4; ++r) {
        v0[r] = (hacc[i][jt][r] + b2v) * SCALE;
        mx = fmaxf(mx, v0[r]);
      }
      mx = fmaxf(mx, __shfl_xor(mx, 16));
      mx = fmaxf(mx, __shfl_xor(mx, 32));
      float ex[4], sum = 0.f;
#pragma unroll
      for (int r = 0; r < 4; ++r) { ex[r] = __expf(v0[r] - mx); sum += ex[r]; }
      sum += __shfl_xor(sum, 16);
      sum += __shfl_xor(sum, 32);
      float inv = 1.0f / sum;
      float vv[4];
      vv[0] = bf2f((short)(vpe_pk[i][jt][0] & 0xffff));
      vv[1] = bf2f((short)(vpe_pk[i][jt][0] >> 16));
      vv[2] = bf2f((short)(vpe_pk[i][jt][1] & 0xffff));
      vv[3] = bf2f((short)(vpe_pk[i][jt][1] >> 16));
      float part = 0.f;
#pragma unroll
      for (int r = 0; r < 4; ++r) part += ex[r] * vv[r];
      part += __shfl_xor(part, 16);
      part += __shfl_xor(part, 32);
      if (q == 0) agg[(size_t)(gp0 + rt) * DIM + col] = part * inv;
    }
  }
}

extern "C" void kernel_launch(void* const* d_in, const int* in_sizes, int n_in,
                              void* d_out, int out_size, void* d_ws, size_t ws_size,
                              hipStream_t stream)
{
  const float* ori_x    = (const float*)d_in[0];
  const float* pos      = (const float*)d_in[1];
  const float* w_in     = (const float*)d_in[2];
  const float* w_qkv    = (const float*)d_in[3];
  const float* w_out    = (const float*)d_in[4];
  const float* pos_w1   = (const float*)d_in[5];
  const float* pos_b1   = (const float*)d_in[6];
  const float* pos_bn_g = (const float*)d_in[7];
  const float* pos_bn_b = (const float*)d_in[8];
  const float* pos_bn_m = (const float*)d_in[9];
  const float* pos_bn_v = (const float*)d_in[10];
  const float* pos_w2   = (const float*)d_in[11];
  const float* pos_b2   = (const float*)d_in[12];
  const float* attn_w1  = (const float*)d_in[13];
  const float* attn_b1  = (const float*)d_in[14];
  const float* attn_bn_g = (const float*)d_in[15];
  const float* attn_bn_b = (const float*)d_in[16];
  const float* attn_bn_m = (const float*)d_in[17];
  const float* attn_bn_v = (const float*)d_in[18];
  const float* attn_w2  = (const float*)d_in[19];
  const float* attn_b2  = (const float*)d_in[20];
  float* out = (float*)d_out;

  float* agg  = (float*)d_ws;                          // [NPTS*128] f32; Wf aliases head
  float* Wf   = agg;                                   // [128*384] (consumed by pack)
  short* qkvb = (short*)(agg + (size_t)NPTS * DIM);    // [NPTS*384] bf16
  int*   idx  = (int*)(qkvb + (size_t)NPTS * 3 * DIM); // [NPTS*16]
  short* w1p  = (short*)(idx + (size_t)NPTS * KNN);
  short* w2p  = w1p + 65536;
  short* pw2p = w2p + 65536;
  short* wfp  = pw2p + 8192;
  short* wop  = wfp + 49152;
  float* biasq = (float*)(wop + 16384);
  float* t1sc = biasq + 384;
  float* t1bi = t1sc + 512;
  float* phsc = t1bi + 512;
  float* phbi = phsc + 64;
  float* pos_t = phbi + 64;                            // [NB*3*NN]

  gemm_f32<<<dim3(2, 6), 256, 0, stream>>>(w_in, w_qkv, Wf, 128, 384, 128);
  transpose_pos<<<(NPTS * 3 + 255) / 256, 256, 0, stream>>>(pos, pos_t);
  pack_weights<<<807, 256, 0, stream>>>(attn_w1, attn_w2, pos_w2, Wf, w_out,
      attn_b1, attn_bn_g, attn_bn_b, attn_bn_m, attn_bn_v,
      pos_b1, pos_bn_g, pos_bn_b, pos_bn_m, pos_bn_v, pos_b2,
      w1p, w2p, pw2p, wfp, wop, biasq, t1sc, t1bi, phsc, phbi);
  gemm_in<<<NPTS / 64, 256, 0, stream>>>(ori_x, wfp, biasq, qkvb);
  knn_kernel<<<NPTS / 4, 256, 0, stream>>>(pos_t, idx);
  fused_attn<<<NPTS / 4, 256, 0, stream>>>(pos, qkvb, idx, pos_w1,
      w1p, w2p, pw2p, t1sc, t1bi, phsc, phbi, attn_b2, agg);
  gemm_out<<<NPTS / 64, 256, 0, stream>>>(agg, wop, ori_x, out);
}

// Round 8
// 360.694 us; speedup vs baseline: 1.5642x; 1.1081x over previous
//
#include <hip/hip_runtime.h>

#define EPS 1e-5f

constexpr int NB   = 8;
constexpr int NN   = 2048;
constexpr int DIM  = 128;
constexpr int KNN  = 16;
constexpr int AH   = 512;
constexpr int NPTS = NB * NN;
constexpr float SCALE = 0.08838834764831845f; // 1/sqrt(128)

typedef __attribute__((ext_vector_type(8))) short short8;
typedef __attribute__((ext_vector_type(4))) float floatx4;

// round-half-up bf16 conversion: 2 VALU ops (vs 5 for full RNE); threshold
// headroom is ~6x and ties are rare — measured absmax stays well under.
__device__ __forceinline__ short f2bf(float f) {
  union { float f; unsigned u; } a; a.f = f;
  return (short)((a.u + 0x8000u) >> 16);
}
__device__ __forceinline__ float bf2f(short s) {
  union { unsigned u; float f; } a; a.u = ((unsigned)(unsigned short)s) << 16;
  return a.f;
}

// ---------------------------------------------------------------------------
// fp32 tiled GEMM (only Wf = w_in @ w_qkv, tiny). 64x64 tile.
// ---------------------------------------------------------------------------
__global__ __launch_bounds__(256) void gemm_f32(
    const float* __restrict__ A, const float* __restrict__ W,
    float* __restrict__ C, int M, int N, int K)
{
  __shared__ float As[64][33];
  __shared__ float Ws[32][65];
  const int bm = blockIdx.x * 64, bn = blockIdx.y * 64;
  const int tid = threadIdx.x;
  const int tx = tid & 15, ty = tid >> 4;
  float acc[4][4] = {};
  for (int k0 = 0; k0 < K; k0 += 32) {
#pragma unroll
    for (int i = 0; i < 8; ++i) {
      int e = tid + i * 256;
      As[e >> 5][e & 31] = A[(size_t)(bm + (e >> 5)) * K + k0 + (e & 31)];
    }
#pragma unroll
    for (int i = 0; i < 8; ++i) {
      int e = tid + i * 256;
      Ws[e >> 6][e & 63] = W[(size_t)(k0 + (e >> 6)) * N + bn + (e & 63)];
    }
    __syncthreads();
#pragma unroll
    for (int kk = 0; kk < 32; ++kk) {
      float a[4], w[4];
#pragma unroll
      for (int i = 0; i < 4; ++i) a[i] = As[ty * 4 + i][kk];
#pragma unroll
      for (int j = 0; j < 4; ++j) w[j] = Ws[kk][tx * 4 + j];
#pragma unroll
      for (int i = 0; i < 4; ++i)
#pragma unroll
        for (int j = 0; j < 4; ++j)
          acc[i][j] += a[i] * w[j];
    }
    __syncthreads();
  }
#pragma unroll
  for (int i = 0; i < 4; ++i)
#pragma unroll
    for (int j = 0; j < 4; ++j)
      C[(size_t)(bm + ty * 4 + i) * N + bn + tx * 4 + j] = acc[i][j];
}

// ---------------------------------------------------------------------------
// KNN: one wave per point; 32 distances/lane in regs (SoA coalesced loads);
// 16 butterfly-argmin rounds; lowest-index tie-break. No LDS/barriers.
// ---------------------------------------------------------------------------
__global__ __launch_bounds__(256) void knn_kernel(
    const float* __restrict__ pos_t, int* __restrict__ idx_out)
{
  const int tid = threadIdx.x;
  const int lane = tid & 63;
  const int p = blockIdx.x * 4 + (tid >> 6);
  const int b = p >> 11, i = p & (NN - 1);
  const float* px = pos_t + (size_t)b * 3 * NN;
  const float* py = px + NN;
  const float* pz = py + NN;
  const float xi = px[i], yi = py[i], zi = pz[i];
  const float sqi = xi * xi + yi * yi + zi * zi;
  float v[32];
#pragma unroll
  for (int t = 0; t < 32; ++t) {
    int j = t * 64 + lane;
    float xj = px[j], yj = py[j], zj = pz[j];
    float sqj = xj * xj + yj * yj + zj * zj;
    float dot = xi * xj + yi * yj + zi * zj;
    v[t] = sqi + sqj - 2.0f * dot;
  }
  for (int s = 0; s < KNN; ++s) {
    float bv = 3.4e38f; int bj = 1 << 30;
#pragma unroll
    for (int t = 0; t < 32; ++t) {
      if (v[t] < bv) { bv = v[t]; bj = t * 64 + lane; }
    }
#pragma unroll
    for (int m = 1; m < 64; m <<= 1) {
      float ov = __shfl_xor(bv, m);
      int   oj = __shfl_xor(bj, m);
      if (ov < bv || (ov == bv && oj < bj)) { bv = ov; bj = oj; }
    }
    if (lane == 0) idx_out[(size_t)p * KNN + s] = bj;
#pragma unroll
    for (int t = 0; t < 32; ++t)
      if (bj == t * 64 + lane) v[t] = 3.4e38f;
  }
}

// ---------------------------------------------------------------------------
// Pack weights into bf16 B-fragment layouts (frag f at [f*512 + lane*8 + j],
// value = W[k = ks*32 + q*8 + j][n]) + folded BN + biases + pos SoA transpose.
// ---------------------------------------------------------------------------
__global__ __launch_bounds__(256) void pack_weights(
    const float* __restrict__ attn_w1, const float* __restrict__ attn_w2,
    const float* __restrict__ pos_w2, const float* __restrict__ Wf,
    const float* __restrict__ w_out, const float* __restrict__ pos,
    const float* __restrict__ attn_b1, const float* __restrict__ abn_g,
    const float* __restrict__ abn_b, const float* __restrict__ abn_m,
    const float* __restrict__ abn_v,
    const float* __restrict__ pos_b1, const float* __restrict__ pbn_g,
    const float* __restrict__ pbn_b, const float* __restrict__ pbn_m,
    const float* __restrict__ pbn_v, const float* __restrict__ pos_b2,
    short* __restrict__ w1p, short* __restrict__ w2p, short* __restrict__ pw2p,
    short* __restrict__ wfp, short* __restrict__ wop,
    float* __restrict__ biasq,
    float* __restrict__ t1sc, float* __restrict__ t1bi,
    float* __restrict__ phsc, float* __restrict__ phbi,
    float* __restrict__ pos_t)
{
  int t = blockIdx.x * 256 + threadIdx.x;
  if (t < 65536) {                       // w1p: [128x512], 8 chunks of 64 cols
    int j = t & 7, lane = (t >> 3) & 63, ks = (t >> 9) & 3, nt = (t >> 11) & 3, ch = t >> 13;
    int q = lane >> 4, cc = lane & 15;
    int k = ks * 32 + q * 8 + j, n = ch * 64 + nt * 16 + cc;
    w1p[t] = f2bf(attn_w1[(size_t)k * AH + n]);
  } else if (t < 131072) {               // w2p: [512x128], 8 chunks of 64 rows
    int e = t - 65536;
    int j = e & 7, lane = (e >> 3) & 63, ks = (e >> 9) & 1, nt = (e >> 10) & 7, ch = e >> 13;
    int q = lane >> 4, cc = lane & 15;
    int k = ch * 64 + ks * 32 + q * 8 + j, n = nt * 16 + cc;
    w2p[e] = f2bf(attn_w2[(size_t)k * DIM + n]);
  } else if (t < 139264) {               // pw2p: pos_w2 [64x128]
    int e = t - 131072;
    int j = e & 7, lane = (e >> 3) & 63, ks = (e >> 9) & 1, nt = e >> 10;
    int q = lane >> 4, cc = lane & 15;
    int k = ks * 32 + q * 8 + j, n = nt * 16 + cc;
    pw2p[e] = f2bf(pos_w2[(size_t)k * DIM + n]);
  } else if (t < 188416) {               // wfp: Wf [128x384], 3 col-chunks
    int e = t - 139264;
    int j = e & 7, lane = (e >> 3) & 63, ks = (e >> 9) & 3, nt = (e >> 11) & 7, nc = e >> 14;
    int q = lane >> 4, cc = lane & 15;
    int k = ks * 32 + q * 8 + j, n = nc * 128 + nt * 16 + cc;
    wfp[e] = f2bf(Wf[(size_t)k * 384 + n]);
  } else if (t < 204800) {               // wop: w_out [128x128]
    int e = t - 188416;
    int j = e & 7, lane = (e >> 3) & 63, ks = (e >> 9) & 3, nt = (e >> 11) & 7;
    int q = lane >> 4, cc = lane & 15;
    int k = ks * 32 + q * 8 + j, n = nt * 16 + cc;
    wop[e] = f2bf(w_out[(size_t)k * DIM + n]);
  } else if (t < 205184) {               // biasq[384]: pos_b2 into q,v cols
    int c = t - 204800;
    biasq[c] = (c < 128) ? pos_b2[c] : ((c < 256) ? 0.0f : pos_b2[c - 256]);
  } else if (t < 205696) {
    int c = t - 205184;
    t1sc[c] = abn_g[c] * rsqrtf(abn_v[c] + EPS);
  } else if (t < 206208) {
    int c = t - 205696;
    float sc = abn_g[c] * rsqrtf(abn_v[c] + EPS);
    t1bi[c] = (attn_b1[c] - abn_m[c]) * sc + abn_b[c];
  } else if (t < 206272) {
    int c = t - 206208;
    phsc[c] = pbn_g[c] * rsqrtf(pbn_v[c] + EPS);
  } else if (t < 206336) {
    int c = t - 206272;
    float sc = pbn_g[c] * rsqrtf(pbn_v[c] + EPS);
    phbi[c] = (pos_b1[c] - pbn_m[c]) * sc + pbn_b[c];
  } else if (t < 206336 + NPTS * 3) {    // pos -> SoA pos_t[b][3][NN]
    int e = t - 206336;
    int p = e / 3, d = e - p * 3;
    int b = p >> 11, n = p & (NN - 1);
    pos_t[((size_t)b * 3 + d) * NN + n] = pos[e];
  }
}

// ---------------------------------------------------------------------------
// MFMA GEMM: qkv[16384x384] (bf16 out) = bf16(ori_x) @ wfp + biasq.
// M=64 blocks; 3 col-chunks looped inside (A staged once).
// ---------------------------------------------------------------------------
__global__ __launch_bounds__(256, 4) void gemm_in(
    const float* __restrict__ A, const short* __restrict__ wfp,
    const float* __restrict__ biasq, short* __restrict__ C)
{
  __shared__ short As[64 * 128];
  const int tid = threadIdx.x;
  const int lane = tid & 63, w = tid >> 6;
  const int wr = w >> 1, wc = w & 1;
  const int q = lane >> 4, cc = lane & 15;
  const int row0 = blockIdx.x * 64;
#pragma unroll
  for (int it = 0; it < 4; ++it) {
    int e = tid + it * 256;
    int row = e >> 4, cg = e & 15;
    const float* src = A + (size_t)(row0 + row) * 128 + cg * 8;
    float4 f0 = *(const float4*)src, f1 = *(const float4*)(src + 4);
    short8 v;
    v[0] = f2bf(f0.x); v[1] = f2bf(f0.y); v[2] = f2bf(f0.z); v[3] = f2bf(f0.w);
    v[4] = f2bf(f1.x); v[5] = f2bf(f1.y); v[6] = f2bf(f1.z); v[7] = f2bf(f1.w);
    *(short8*)(As + row * 128 + ((cg ^ (row & 15)) << 3)) = v;
  }
  __syncthreads();
  for (int nc = 0; nc < 3; ++nc) {
    floatx4 acc[2][4];
#pragma unroll
    for (int i = 0; i < 2; ++i)
#pragma unroll
      for (int jt = 0; jt < 4; ++jt) acc[i][jt] = (floatx4){0.f, 0.f, 0.f, 0.f};
#pragma unroll
    for (int ks = 0; ks < 4; ++ks) {
      short8 a8[2], b8[4];
#pragma unroll
      for (int i = 0; i < 2; ++i) {
        int row = (wr * 2 + i) * 16 + cc;
        a8[i] = *(const short8*)(As + row * 128 + (((ks * 4 + q) ^ cc) << 3));
      }
#pragma unroll
      for (int jt = 0; jt < 4; ++jt)
        b8[jt] = *(const short8*)(wfp + ((((nc * 8 + wc * 4 + jt) * 4 + ks) * 64 + lane) << 3));
#pragma unroll
      for (int i = 0; i < 2; ++i)
#pragma unroll
        for (int jt = 0; jt < 4; ++jt)
          acc[i][jt] = __builtin_amdgcn_mfma_f32_16x16x32_bf16(a8[i], b8[jt], acc[i][jt], 0, 0, 0);
    }
#pragma unroll
    for (int jt = 0; jt < 4; ++jt) {
      int colG = nc * 128 + (wc * 4 + jt) * 16 + cc;
      float bv = biasq[colG];
#pragma unroll
      for (int i = 0; i < 2; ++i)
#pragma unroll
        for (int r = 0; r < 4; ++r) {
          int row = (wr * 2 + i) * 16 + q * 4 + r;
          C[(size_t)(row0 + row) * 384 + colG] = f2bf(acc[i][jt][r] + bv);
        }
    }
  }
}

// ---------------------------------------------------------------------------
// MFMA GEMM: out[16384x128] = bf16(agg) @ wop + ori_x. M=64 blocks.
// ---------------------------------------------------------------------------
__global__ __launch_bounds__(256, 4) void gemm_out(
    const float* __restrict__ A, const short* __restrict__ wop,
    const float* __restrict__ R, float* __restrict__ C)
{
  __shared__ short As[64 * 128];
  const int tid = threadIdx.x;
  const int lane = tid & 63, w = tid >> 6;
  const int wr = w >> 1, wc = w & 1;
  const int q = lane >> 4, cc = lane & 15;
  const int row0 = blockIdx.x * 64;
#pragma unroll
  for (int it = 0; it < 4; ++it) {
    int e = tid + it * 256;
    int row = e >> 4, cg = e & 15;
    const float* src = A + (size_t)(row0 + row) * 128 + cg * 8;
    float4 f0 = *(const float4*)src, f1 = *(const float4*)(src + 4);
    short8 v;
    v[0] = f2bf(f0.x); v[1] = f2bf(f0.y); v[2] = f2bf(f0.z); v[3] = f2bf(f0.w);
    v[4] = f2bf(f1.x); v[5] = f2bf(f1.y); v[6] = f2bf(f1.z); v[7] = f2bf(f1.w);
    *(short8*)(As + row * 128 + ((cg ^ (row & 15)) << 3)) = v;
  }
  __syncthreads();
  floatx4 acc[2][4];
#pragma unroll
  for (int i = 0; i < 2; ++i)
#pragma unroll
    for (int jt = 0; jt < 4; ++jt) acc[i][jt] = (floatx4){0.f, 0.f, 0.f, 0.f};
#pragma unroll
  for (int ks = 0; ks < 4; ++ks) {
    short8 a8[2], b8[4];
#pragma unroll
    for (int i = 0; i < 2; ++i) {
      int row = (wr * 2 + i) * 16 + cc;
      a8[i] = *(const short8*)(As + row * 128 + (((ks * 4 + q) ^ cc) << 3));
    }
#pragma unroll
    for (int jt = 0; jt < 4; ++jt)
      b8[jt] = *(const short8*)(wop + ((((wc * 4 + jt) * 4 + ks) * 64 + lane) << 3));
#pragma unroll
    for (int i = 0; i < 2; ++i)
#pragma unroll
      for (int jt = 0; jt < 4; ++jt)
        acc[i][jt] = __builtin_amdgcn_mfma_f32_16x16x32_bf16(a8[i], b8[jt], acc[i][jt], 0, 0, 0);
  }
#pragma unroll
  for (int jt = 0; jt < 4; ++jt) {
    int col = (wc * 4 + jt) * 16 + cc;
#pragma unroll
    for (int i = 0; i < 2; ++i)
#pragma unroll
      for (int r = 0; r < 4; ++r) {
        int row = (wr * 2 + i) * 16 + q * 4 + r;
        size_t o = (size_t)(row0 + row) * 128 + col;
        C[o] = acc[i][jt][r] + R[o];
      }
  }
}

// ---------------------------------------------------------------------------
// Fused MFMA attention: 4 points/block (M=64), 4 waves each 32x64, 64-col AH
// chunks, double-buffered t1. vpe lives in LDS (not regs) so no value spans
// the 8-chunk main loop -> no long-live-range spill. LDS ~50 KB, 3 blocks/CU.
// XCD-affinity: batch = blockIdx.x & 7.
// ---------------------------------------------------------------------------
__global__ __launch_bounds__(256, 3) void fused_attn(
    const float* __restrict__ pos, const short* __restrict__ qkv,
    const int* __restrict__ knn_idx,
    const float* __restrict__ pos_w1,
    const short* __restrict__ w1p, const short* __restrict__ w2p,
    const short* __restrict__ pw2p,
    const float* __restrict__ t1sc, const float* __restrict__ t1bi,
    const float* __restrict__ phsc, const float* __restrict__ phbi,
    const float* __restrict__ attn_b2,
    float* __restrict__ agg)
{
  __shared__ short a_s[64 * 128];       // 16 KB, XOR swizzle on row&15
  __shared__ short vpe_s[64 * 128];     // 16 KB, same swizzle
  __shared__ short t1_s[2][64 * 64];    // 16 KB, XOR swizzle on row&7
  __shared__ short q_ss[4 * 128];       // 1 KB bf16 q rows
  __shared__ float relp_s[64 * 4];
  __shared__ int   nbr_s[64];

  const int tid = threadIdx.x;
  const int lane = tid & 63, w = tid >> 6;
  const int wr = w >> 1, wc = w & 1;
  const int q = lane >> 4, cc = lane & 15;
  const int bb = blockIdx.x & 7;                     // XCD-affinity swizzle
  const int gp0 = bb * NN + (blockIdx.x >> 3) * 4;   // 4 points/block

  if (tid < 64) nbr_s[tid] = knn_idx[(size_t)gp0 * KNN + tid];
  if (tid >= 64 && tid < 128) {  // stage q rows (bf16)
    int e = tid - 64;
    int p = e >> 4, seg = e & 15;
    *(short8*)(q_ss + p * 128 + seg * 8) =
        *(const short8*)(qkv + (size_t)(gp0 + p) * 384 + seg * 8);
  }
  __syncthreads();
  if (tid < 64) {
    int p = tid >> 4;
    int j = nbr_s[tid];
    const float* pa = pos + (size_t)(gp0 + p) * 3;
    const float* pj = pos + ((size_t)bb * NN + j) * 3;
    relp_s[tid * 4 + 0] = pa[0] - pj[0];
    relp_s[tid * 4 + 1] = pa[1] - pj[1];
    relp_s[tid * 4 + 2] = pa[2] - pj[2];
  }
  __syncthreads();

  // ph = relu(bn(relp @ pos_w1 + b1)) -> t1_s[0] (64 rows x 64 cols)
#pragma unroll
  for (int r2 = 0; r2 < 16; ++r2) {
    int e = tid + r2 * 256;
    int row = e >> 6, c = e & 63;
    float lin = relp_s[row * 4] * pos_w1[c] + relp_s[row * 4 + 1] * pos_w1[64 + c]
              + relp_s[row * 4 + 2] * pos_w1[128 + c];
    t1_s[0][row * 64 + (((c >> 3) ^ (row & 7)) << 3) + (c & 7)] =
        f2bf(fmaxf(lin * phsc[c] + phbi[c], 0.0f));
  }
  __syncthreads();

  // pe = ph @ pos_w2 (pos_b2 pre-folded into qkv q/v cols)
  floatx4 pe[2][4];
#pragma unroll
  for (int i = 0; i < 2; ++i)
#pragma unroll
    for (int jt = 0; jt < 4; ++jt) pe[i][jt] = (floatx4){0.f, 0.f, 0.f, 0.f};
#pragma unroll
  for (int ks = 0; ks < 2; ++ks) {
    short8 a8[2];
#pragma unroll
    for (int i = 0; i < 2; ++i) {
      int row = (wr * 2 + i) * 16 + cc;
      a8[i] = *(const short8*)(t1_s[0] + row * 64 + (((ks * 4 + q) ^ (row & 7)) << 3));
    }
#pragma unroll
    for (int jt = 0; jt < 4; ++jt) {
      short8 b8 = *(const short8*)(pw2p + ((((wc * 4 + jt) * 2 + ks) * 64 + lane) << 3));
#pragma unroll
      for (int i = 0; i < 2; ++i)
        pe[i][jt] = __builtin_amdgcn_mfma_f32_16x16x32_bf16(a8[i], b8, pe[i][jt], 0, 0, 0);
    }
  }

  // combine: a = q - k_g + pe -> a_s ; vpe = v_g + pe -> vpe_s (LDS, no regs)
#pragma unroll
  for (int i = 0; i < 2; ++i) {
    int rt = wr * 2 + i;
#pragma unroll
    for (int jt = 0; jt < 4; ++jt) {
      int col = (wc * 4 + jt) * 16 + cc;
      float qv = bf2f(q_ss[rt * 128 + col]);
#pragma unroll
      for (int r = 0; r < 4; ++r) {
        int row = rt * 16 + q * 4 + r;
        const short* kv = qkv + ((size_t)bb * NN + nbr_s[row]) * 384;
        float pev = pe[i][jt][r];
        int slot = row * 128 + (((col >> 3) ^ (row & 15)) << 3) + (col & 7);
        a_s[slot]   = f2bf(qv - bf2f(kv[128 + col]) + pev);
        vpe_s[slot] = f2bf(bf2f(kv[256 + col]) + pev);
      }
    }
  }
  __syncthreads();   // a_s fully built; pe reads of t1_s[0] complete

  floatx4 hacc[2][4];
#pragma unroll
  for (int i = 0; i < 2; ++i)
#pragma unroll
    for (int jt = 0; jt < 4; ++jt) hacc[i][jt] = (floatx4){0.f, 0.f, 0.f, 0.f};

  for (int ch = 0; ch < 8; ++ch) {
    short* t1b = t1_s[ch & 1];
    // GEMM1: tacc = a @ w1[:, ch*64 : +64]  (wave covers 32 rows x 32 cols)
    floatx4 tacc[2][2];
#pragma unroll
    for (int i = 0; i < 2; ++i)
#pragma unroll
      for (int jt = 0; jt < 2; ++jt) tacc[i][jt] = (floatx4){0.f, 0.f, 0.f, 0.f};
#pragma unroll
    for (int ks = 0; ks < 4; ++ks) {
      short8 a8[2], b8[2];
#pragma unroll
      for (int i = 0; i < 2; ++i) {
        int row = (wr * 2 + i) * 16 + cc;
        a8[i] = *(const short8*)(a_s + row * 128 + (((ks * 4 + q) ^ cc) << 3));
      }
#pragma unroll
      for (int jt = 0; jt < 2; ++jt)
        b8[jt] = *(const short8*)(w1p + ((((ch * 4 + wc * 2 + jt) * 4 + ks) * 64 + lane) << 3));
#pragma unroll
      for (int i = 0; i < 2; ++i)
#pragma unroll
        for (int jt = 0; jt < 2; ++jt)
          tacc[i][jt] = __builtin_amdgcn_mfma_f32_16x16x32_bf16(a8[i], b8[jt], tacc[i][jt], 0, 0, 0);
    }
    // bn/relu -> t1b (64-col, swizzled)
#pragma unroll
    for (int jt = 0; jt < 2; ++jt) {
      int colL = (wc * 2 + jt) * 16 + cc;
      int colG = ch * 64 + colL;
      float sc = t1sc[colG], bi = t1bi[colG];
#pragma unroll
      for (int i = 0; i < 2; ++i)
#pragma unroll
        for (int r = 0; r < 4; ++r) {
          int row = (wr * 2 + i) * 16 + q * 4 + r;
          t1b[row * 64 + (((colL >> 3) ^ (row & 7)) << 3) + (colL & 7)] =
              f2bf(fmaxf(tacc[i][jt][r] * sc + bi, 0.0f));
        }
    }
    __syncthreads();   // t1b visible; ping-pong protects in-flight reads
    // GEMM2: hacc += t1 @ w2[ch*64 : +64, :]
#pragma unroll
    for (int ks = 0; ks < 2; ++ks) {
      short8 a8[2], b8[4];
#pragma unroll
      for (int i = 0; i < 2; ++i) {
        int row = (wr * 2 + i) * 16 + cc;
        a8[i] = *(const short8*)(t1b + row * 64 + (((ks * 4 + q) ^ (row & 7)) << 3));
      }
#pragma unroll
      for (int jt = 0; jt < 4; ++jt)
        b8[jt] = *(const short8*)(w2p + ((((ch * 8 + wc * 4 + jt) * 2 + ks) * 64 + lane) << 3));
#pragma unroll
      for (int i = 0; i < 2; ++i)
#pragma unroll
        for (int jt = 0; jt < 4; ++jt)
          hacc[i][jt] = __builtin_amdgcn_mfma_f32_16x16x32_bf16(a8[i], b8[jt], hacc[i][jt], 0, 0, 0);
    }
  }

  // softmax over the 16 neighbors per (point, channel) + aggregate
#pragma unroll
  for (int i = 0; i < 2; ++i) {
    int rt = wr * 2 + i;
#pragma unroll
    for (int jt = 0; jt < 4; ++jt) {
      int col = (wc * 4 + jt) * 16 + cc;
      float b2v = attn_b2[col];
      float v0[4], mx = -3.4e38f;
#pragma unroll
      for (int r = 0; r < 4; ++r) {
        v0[r] = (hacc[i][jt][r] + b2v) * SCALE;
        mx = fmaxf(mx, v0[r]);
      }
      mx = fmaxf(mx, __shfl_xor(mx, 16));
      mx = fmaxf(mx, __shfl_xor(mx, 32));
      float ex[4], sum = 0.f;
#pragma unroll
      for (int r = 0; r < 4; ++r) { ex[r] = __expf(v0[r] - mx); sum += ex[r]; }
      sum += __shfl_xor(sum, 16);
      sum += __shfl_xor(sum, 32);
      float inv = 1.0f / sum;
      float part = 0.f;
#pragma unroll
      for (int r = 0; r < 4; ++r) {
        int row = rt * 16 + q * 4 + r;
        int slot = row * 128 + (((col >> 3) ^ (row & 15)) << 3) + (col & 7);
        part += ex[r] * bf2f(vpe_s[slot]);
      }
      part += __shfl_xor(part, 16);
      part += __shfl_xor(part, 32);
      if (q == 0) agg[(size_t)(gp0 + rt) * DIM + col] = part * inv;
    }
  }
}

extern "C" void kernel_launch(void* const* d_in, const int* in_sizes, int n_in,
                              void* d_out, int out_size, void* d_ws, size_t ws_size,
                              hipStream_t stream)
{
  const float* ori_x    = (const float*)d_in[0];
  const float* pos      = (const float*)d_in[1];
  const float* w_in     = (const float*)d_in[2];
  const float* w_qkv    = (const float*)d_in[3];
  const float* w_out    = (const float*)d_in[4];
  const float* pos_w1   = (const float*)d_in[5];
  const float* pos_b1   = (const float*)d_in[6];
  const float* pos_bn_g = (const float*)d_in[7];
  const float* pos_bn_b = (const float*)d_in[8];
  const float* pos_bn_m = (const float*)d_in[9];
  const float* pos_bn_v = (const float*)d_in[10];
  const float* pos_w2   = (const float*)d_in[11];
  const float* pos_b2   = (const float*)d_in[12];
  const float* attn_w1  = (const float*)d_in[13];
  const float* attn_b1  = (const float*)d_in[14];
  const float* attn_bn_g = (const float*)d_in[15];
  const float* attn_bn_b = (const float*)d_in[16];
  const float* attn_bn_m = (const float*)d_in[17];
  const float* attn_bn_v = (const float*)d_in[18];
  const float* attn_w2  = (const float*)d_in[19];
  const float* attn_b2  = (const float*)d_in[20];
  float* out = (float*)d_out;

  float* agg  = (float*)d_ws;                          // [NPTS*128] f32; Wf aliases head
  float* Wf   = agg;                                   // [128*384] (consumed by pack)
  short* qkvb = (short*)(agg + (size_t)NPTS * DIM);    // [NPTS*384] bf16
  int*   idx  = (int*)(qkvb + (size_t)NPTS * 3 * DIM); // [NPTS*16]
  short* w1p  = (short*)(idx + (size_t)NPTS * KNN);
  short* w2p  = w1p + 65536;
  short* pw2p = w2p + 65536;
  short* wfp  = pw2p + 8192;
  short* wop  = wfp + 49152;
  float* biasq = (float*)(wop + 16384);
  float* t1sc = biasq + 384;
  float* t1bi = t1sc + 512;
  float* phsc = t1bi + 512;
  float* phbi = phsc + 64;
  float* pos_t = phbi + 64;                            // [NB*3*NN]

  gemm_f32<<<dim3(2, 6), 256, 0, stream>>>(w_in, w_qkv, Wf, 128, 384, 128);
  pack_weights<<<998, 256, 0, stream>>>(attn_w1, attn_w2, pos_w2, Wf, w_out, pos,
      attn_b1, attn_bn_g, attn_bn_b, attn_bn_m, attn_bn_v,
      pos_b1, pos_bn_g, pos_bn_b, pos_bn_m, pos_bn_v, pos_b2,
      w1p, w2p, pw2p, wfp, wop, biasq, t1sc, t1bi, phsc, phbi, pos_t);
  gemm_in<<<NPTS / 64, 256, 0, stream>>>(ori_x, wfp, biasq, qkvb);
  knn_kernel<<<NPTS / 4, 256, 0, stream>>>(pos_t, idx);
  fused_attn<<<NPTS / 4, 256, 0, stream>>>(pos, qkvb, idx, pos_w1,
      w1p, w2p, pw2p, t1sc, t1bi, phsc, phbi, attn_b2, agg);
  gemm_out<<<NPTS / 64, 256, 0, stream>>>(agg, wop, ori_x, out);
}